// Round 7
// baseline (6805.038 us; speedup 1.0000x reference)
//
#include <hip/hip_runtime.h>
#include <hip/hip_fp16.h>

// FixedFreqModel: B=512, L=2048, M=256, H=64, VOCAB=64, READ_FREQ=16.
// R7: TWO batch chains per wave (256 blocks x 64 thr). The chains are
// independent -> their instruction streams interleave and cover each other's
// latency stalls (R6 evidence: single chain only keeps its SIMD ~35% busy).
// Shared between chains: W_hh regs, WR/QP loads, biases. Per chain: kT fp16
// in LDS (32 KB each), v fp16 streamed from global (L2-resident 64 KB/block),
// h/q/p/ret LDS scratch. Also: rcp-based sigmoid/tanh/softmax (no fp32 div),
// softmax without max-subtraction (|s| <~ 10, exp safe in fp32).

#define B_ 512
#define L_ 2048
#define M_ 256
#define H_ 64
#define C_ 128
#define F_ 16

typedef float v2f __attribute__((ext_vector_type(2)));

// workspace offsets (bytes)
#define WS_KT    0u            // 512*16384 halves = 16 MB
#define WS_V     16777216u     // 16 MB
#define WS_G     33554432u     // 64*192 fp32 = 48 KB
#define WS_WPHH  33603584u     // 3072 float4 = 48 KB
#define WS_WR    33652736u     // 3072 float4 = 48 KB
#define WS_QP    33701888u     // 1024 * 8B (half4) = 8 KB
#define WS_KWP   33710080u     // 1024 float4 = 16 KB
#define WS_VWP   33726464u     // 16 KB

// dynamic LDS layout (bytes)
#define S_KT0   0u        // 32768 : kT chain0, half [hh][m] (64 x 256)
#define S_KT1   32768u    // 32768 : kT chain1
#define S_QP    65536u    // 8192  : QP half4 [k4][j] (shared)
#define S_P0    73728u    // 1024  : float4 p0[64]
#define S_P1    74752u    // 1024
#define S_H0    75776u    // 256
#define S_H1    76032u    // 256
#define S_RET0  76288u    // 256
#define S_RET1  76544u    // 256
#define S_Q0    76800u    // 256
#define S_Q1    77056u    // 256
#define SMEM_BYTES 77312u   // <= 80 KB -> 2 blocks/CU

__device__ __forceinline__ float dot4(float4 a, float4 b) {
    return a.x*b.x + a.y*b.y + a.z*b.z + a.w*b.w;
}
__device__ __forceinline__ void cvt2v(uint2 raw, v2f& lo, v2f& hi) {
    __half2* hp = (__half2*)&raw;
    float2 a = __half22float2(hp[0]);
    float2 b = __half22float2(hp[1]);
    lo[0] = a.x; lo[1] = a.y; hi[0] = b.x; hi[1] = b.y;
}
__device__ __forceinline__ float fast_rcp(float x) { return __builtin_amdgcn_rcpf(x); }
__device__ __forceinline__ float sigm(float x) { return fast_rcp(1.f + __expf(-x)); }
__device__ __forceinline__ float tanh_f(float x) {
    float e2 = __expf(-2.f * fabsf(x));
    return copysignf((1.f - e2) * fast_rcp(1.f + e2), x);
}

// ---------------- pack weights -----------------------------------------------
__global__ void pack_weights(const float* __restrict__ w_ih,
                             const float* __restrict__ w_hh,
                             const float* __restrict__ qw,
                             const float* __restrict__ kw,
                             const float* __restrict__ vw,
                             float4* __restrict__ WPhh,
                             float4* __restrict__ WR,
                             __half2* __restrict__ QPh,
                             float4* __restrict__ KWP,
                             float4* __restrict__ VWP)
{
    int idx = blockIdx.x * 256 + threadIdx.x;
    if (idx < 3072) {                       // WPhh[(k4*3+g)*64+j] = w_hh[(g*64+j)][4k4..]
        int j = idx & 63, kg = idx >> 6, g = kg % 3, k4 = kg / 3;
        const float* s = w_hh + (g*64 + j)*64 + 4*k4;
        WPhh[idx] = make_float4(s[0], s[1], s[2], s[3]);
    } else if (idx < 6144) {                // WR: retrieved half of w_ih (cols 64..127)
        int i = idx - 3072;
        int j = i & 63, kg = i >> 6, g = kg % 3, k4 = kg / 3;
        const float* s = w_ih + (g*64 + j)*128 + 64 + 4*k4;
        WR[i] = make_float4(s[0], s[1], s[2], s[3]);
    } else if (idx < 7168) {                // QPh: half4 of qw[j][4k4..]
        int i = idx - 6144;
        int j = i & 63, k4 = i >> 6;
        const float* s = qw + j*64 + 4*k4;
        QPh[i*2]     = __floats2half2_rn(s[0], s[1]);
        QPh[i*2 + 1] = __floats2half2_rn(s[2], s[3]);
    } else if (idx < 8192) {
        int i = idx - 7168;
        int j = i & 63, k4 = i >> 6;
        const float* s = kw + j*64 + 4*k4;
        KWP[i] = make_float4(s[0], s[1], s[2], s[3]);
    } else if (idx < 9216) {
        int i = idx - 8192;
        int j = i & 63, k4 = i >> 6;
        const float* s = vw + j*64 + 4*k4;
        VWP[i] = make_float4(s[0], s[1], s[2], s[3]);
    }
}

// ---------------- G[v][o] = sum_k embed[v][k]*w_ih[o][k] + b_ih[o] ----------
__global__ __launch_bounds__(64) void build_G(const float* __restrict__ embed_w,
                                              const float* __restrict__ w_ih,
                                              const float* __restrict__ b_ih,
                                              float* __restrict__ G)
{
    int v = blockIdx.x, j = threadIdx.x;
    __shared__ float e_s[64];
    e_s[j] = embed_w[v*64 + j];
    __syncthreads();
    float a0 = b_ih[j], a1 = b_ih[64 + j], a2 = b_ih[128 + j];
    for (int k = 0; k < 64; ++k) {
        float e = e_s[k];
        a0 += e * w_ih[j*128 + k];
        a1 += e * w_ih[(64 + j)*128 + k];
        a2 += e * w_ih[(128 + j)*128 + k];
    }
    G[v*192 + j]       = a0;
    G[v*192 + 64 + j]  = a1;
    G[v*192 + 128 + j] = a2;
}

// ---------------- k/v precompute (fp16 outputs) ------------------------------
__global__ __launch_bounds__(256) void compute_kv(const float* __restrict__ memory,
                                                  const float* __restrict__ key_b,
                                                  const float* __restrict__ val_b,
                                                  const float4* __restrict__ KWP,
                                                  const float4* __restrict__ VWP,
                                                  __half* __restrict__ kT_h,
                                                  __half* __restrict__ v_h)
{
    int wid = threadIdx.x >> 6;
    int o   = threadIdx.x & 63;
    int row = blockIdx.x * 4 + wid;          // row = b*256 + m
    int b = row >> 8, m = row & 255;
    __shared__ __align__(16) float mem_s[4][64];
    mem_s[wid][o] = memory[(size_t)row * 64 + o];
    __syncthreads();
    float ak = key_b[o], av = val_b[o];
    const float4* m4 = (const float4*)mem_s[wid];
#pragma unroll
    for (int k4 = 0; k4 < 16; ++k4) {
        float4 mm = m4[k4];
        ak += dot4(mm, KWP[k4*64 + o]);
        av += dot4(mm, VWP[k4*64 + o]);
    }
    kT_h[((size_t)b*64 + o)*256 + m] = __float2half(ak);  // scattered, one-time
    v_h[(size_t)row*64 + o]          = __float2half(av);  // coalesced
}

// ---------------- main recurrent kernel: TWO chains per wave -----------------
__global__ __launch_bounds__(64, 1) void recurrent_main(
    const int*   __restrict__ seq,
    const float* __restrict__ b_hh,
    const float* __restrict__ query_b,
    const float* __restrict__ head_w,
    const float* __restrict__ head_b,
    const __half* __restrict__ kT_h,
    const __half* __restrict__ v_h,
    const float* __restrict__ G,
    const float4* __restrict__ WPhh,
    const float4* __restrict__ WR,
    float* __restrict__ out)
{
    const int blk = blockIdx.x;
    const int b0 = blk*2, b1 = blk*2 + 1;
    const int j = threadIdx.x;

    extern __shared__ __align__(16) char smem[];
    const uint2* kT0_u2 = (const uint2*)(smem + S_KT0);
    const uint2* kT1_u2 = (const uint2*)(smem + S_KT1);
    const uint2* qp_u2  = (const uint2*)(smem + S_QP);
    float4* p0_s4 = (float4*)(smem + S_P0);
    float4* p1_s4 = (float4*)(smem + S_P1);
    float*  h0_s  = (float*)(smem + S_H0);
    float*  h1_s  = (float*)(smem + S_H1);
    float*  ret0_s = (float*)(smem + S_RET0);
    float*  ret1_s = (float*)(smem + S_RET1);
    float*  q0_s  = (float*)(smem + S_Q0);
    float*  q1_s  = (float*)(smem + S_Q1);

    // ---- stage kT (both chains) + QP into LDS once ----
    {
        const uint4* kTg0 = (const uint4*)(kT_h + (size_t)b0 * 16384);
        const uint4* kTg1 = (const uint4*)(kT_h + (size_t)b1 * 16384);
        uint4* k0ls = (uint4*)(smem + S_KT0);
        uint4* k1ls = (uint4*)(smem + S_KT1);
#pragma unroll
        for (int i = 0; i < 32; ++i) {
            k0ls[i*64 + j] = kTg0[i*64 + j];
            k1ls[i*64 + j] = kTg1[i*64 + j];
        }
        const uint4* qpg = (const uint4*)((const char*)WPhh + (WS_QP - WS_WPHH));
        uint4* qls = (uint4*)(smem + S_QP);
#pragma unroll
        for (int i = 0; i < 8; ++i) qls[i*64 + j] = qpg[i*64 + j];
    }

    // ---- W_hh in registers (shared by both chains): 96 v2f = 192 VGPRs ----
    v2f wrv[32], wzv[32], wnv[32];
#pragma unroll
    for (int k4 = 0; k4 < 16; ++k4) {
        float4 a = WPhh[(k4*3 + 0)*64 + j];
        float4 bq = WPhh[(k4*3 + 1)*64 + j];
        float4 cq = WPhh[(k4*3 + 2)*64 + j];
        wrv[2*k4][0] = a.x;  wrv[2*k4][1] = a.y;
        wrv[2*k4+1][0] = a.z; wrv[2*k4+1][1] = a.w;
        wzv[2*k4][0] = bq.x; wzv[2*k4][1] = bq.y;
        wzv[2*k4+1][0] = bq.z; wzv[2*k4+1][1] = bq.w;
        wnv[2*k4][0] = cq.x; wnv[2*k4][1] = cq.y;
        wnv[2*k4+1][0] = cq.z; wnv[2*k4+1][1] = cq.w;
    }

    float h0 = 0.f, h1 = 0.f;
    h0_s[j] = 0.f; h1_s[j] = 0.f;
    const float bhr = b_hh[j], bhz = b_hh[64 + j], bhn = b_hh[128 + j];
    const float qb  = query_b[j];
    __builtin_amdgcn_wave_barrier();

    const int* seqb0 = seq + (size_t)b0 * L_;
    const int* seqb1 = seq + (size_t)b1 * L_;
    const float4* h4_0 = (const float4*)h0_s;
    const float4* h4_1 = (const float4*)h1_s;
    const float4* r4_0 = (const float4*)ret0_s;
    const float4* r4_1 = (const float4*)ret1_s;
    const float4* q0f4 = (const float4*)q0_s;
    const float4* q1f4 = (const float4*)q1_s;
    const uint2* vg0 = (const uint2*)(v_h + (size_t)b0 * 16384);  // [m*16 + o4]
    const uint2* vg1 = (const uint2*)(v_h + (size_t)b1 * 16384);

    const int o4 = j & 15;        // h-quad owned in v-loop
    const int mg = j >> 4;        // m-group 0..3

    for (int c = 0; c < C_; ++c) {
        // ---- tokens (static after unroll -> registers) ----
        int toks0[F_], toks1[F_];
#pragma unroll
        for (int t = 0; t < F_; ++t) { toks0[t] = seqb0[c*F_ + t]; toks1[t] = seqb1[c*F_ + t]; }

        // ---- q = h @ Wq^T + qb (both chains, shared QP loads) ----
        {
            v2f qa0 = {qb, 0.f}, qc0 = {0.f, 0.f};
            v2f qa1 = {qb, 0.f}, qc1 = {0.f, 0.f};
#pragma unroll
            for (int k4 = 0; k4 < 16; ++k4) {
                float4 hh0 = h4_0[k4];
                float4 hh1 = h4_1[k4];
                v2f plo, phi; cvt2v(qp_u2[k4*64 + j], plo, phi);
                v2f h0A; h0A[0] = hh0.x; h0A[1] = hh0.y;
                v2f h0B; h0B[0] = hh0.z; h0B[1] = hh0.w;
                v2f h1A; h1A[0] = hh1.x; h1A[1] = hh1.y;
                v2f h1B; h1B[0] = hh1.z; h1B[1] = hh1.w;
                qa0 += h0A * plo; qc0 += h0B * phi;
                qa1 += h1A * plo; qc1 += h1B * phi;
            }
            q0_s[j] = (qa0[0] + qc0[0]) + (qa0[1] + qc0[1]);
            q1_s[j] = (qa1[0] + qc1[0]) + (qa1[1] + qc1[1]);
        }
        __builtin_amdgcn_wave_barrier();

        // ---- scores (both chains; lane j owns m = 4j..4j+3) ----
        v2f s01_0 = {0.f,0.f}, s23_0 = {0.f,0.f};
        v2f s01_1 = {0.f,0.f}, s23_1 = {0.f,0.f};
#pragma unroll 4
        for (int hq = 0; hq < 16; ++hq) {
            float4 qq0 = q0f4[hq];
            float4 qq1 = q1f4[hq];
#pragma unroll
            for (int i = 0; i < 4; ++i) {
                v2f kl0, kh0, kl1, kh1;
                cvt2v(kT0_u2[(4*hq + i)*64 + j], kl0, kh0);
                cvt2v(kT1_u2[(4*hq + i)*64 + j], kl1, kh1);
                float q0c = (i == 0) ? qq0.x : (i == 1) ? qq0.y : (i == 2) ? qq0.z : qq0.w;
                float q1c = (i == 0) ? qq1.x : (i == 1) ? qq1.y : (i == 2) ? qq1.z : qq1.w;
                s01_0 += kl0 * q0c; s23_0 += kh0 * q0c;
                s01_1 += kl1 * q1c; s23_1 += kh1 * q1c;
            }
        }
        const float scale = 0.125f;
        // ---- softmax (no max-sub: |s| <= ~10, exp safe in fp32) ----
        float4 p0, p1;
        p0.x = __expf(s01_0[0]*scale); p0.y = __expf(s01_0[1]*scale);
        p0.z = __expf(s23_0[0]*scale); p0.w = __expf(s23_0[1]*scale);
        p1.x = __expf(s01_1[0]*scale); p1.y = __expf(s01_1[1]*scale);
        p1.z = __expf(s23_1[0]*scale); p1.w = __expf(s23_1[1]*scale);
        float sum0 = (p0.x + p0.y) + (p0.z + p0.w);
        float sum1 = (p1.x + p1.y) + (p1.z + p1.w);
#pragma unroll
        for (int o = 32; o > 0; o >>= 1) {
            sum0 += __shfl_xor(sum0, o);
            sum1 += __shfl_xor(sum1, o);
        }
        float inv0 = fast_rcp(sum0);
        float inv1 = fast_rcp(sum1);
        p0_s4[j] = p0;
        p1_s4[j] = p1;
        __builtin_amdgcn_wave_barrier();

        // ---- retrieved: v from GLOBAL (L2-hot), both chains ----
        const float* ps0 = (const float*)p0_s4;
        const float* ps1 = (const float*)p1_s4;
        v2f aA0 = {0.f,0.f}, aB0 = {0.f,0.f};
        v2f aA1 = {0.f,0.f}, aB1 = {0.f,0.f};
#pragma unroll 8
        for (int i = 0; i < 64; ++i) {
            int m = 4*i + mg;
            float pw0 = ps0[m], pw1 = ps1[m];
            v2f v0l, v0h, v1l, v1h;
            cvt2v(vg0[m*16 + o4], v0l, v0h);
            cvt2v(vg1[m*16 + o4], v1l, v1h);
            aA0 += v0l * pw0; aB0 += v0h * pw0;
            aA1 += v1l * pw1; aB1 += v1h * pw1;
        }
        float4 acc0, acc1;
        acc0.x = aA0[0]*inv0; acc0.y = aA0[1]*inv0; acc0.z = aB0[0]*inv0; acc0.w = aB0[1]*inv0;
        acc1.x = aA1[0]*inv1; acc1.y = aA1[1]*inv1; acc1.z = aB1[0]*inv1; acc1.w = aB1[1]*inv1;
#pragma unroll
        for (int o = 16; o <= 32; o <<= 1) {
            acc0.x += __shfl_xor(acc0.x, o); acc0.y += __shfl_xor(acc0.y, o);
            acc0.z += __shfl_xor(acc0.z, o); acc0.w += __shfl_xor(acc0.w, o);
            acc1.x += __shfl_xor(acc1.x, o); acc1.y += __shfl_xor(acc1.y, o);
            acc1.z += __shfl_xor(acc1.z, o); acc1.w += __shfl_xor(acc1.w, o);
        }
        if (j < 16) ((float4*)ret0_s)[j] = acc0;
        else if (j < 32) ((float4*)ret1_s)[j - 16] = acc1;
        __builtin_amdgcn_wave_barrier();

        // ---- R = W_r @ ret (both chains, shared WR loads) ----
        float Rr0, Rz0, Rn0, Rr1, Rz1, Rn1;
        {
            v2f r20 = {0.f,0.f}, z20 = {0.f,0.f}, n20 = {0.f,0.f};
            v2f r21 = {0.f,0.f}, z21 = {0.f,0.f}, n21 = {0.f,0.f};
#pragma unroll
            for (int k4 = 0; k4 < 16; ++k4) {
                float4 rr0 = r4_0[k4];
                float4 rr1 = r4_1[k4];
                float4 w0 = WR[(k4*3 + 0)*64 + j];
                float4 w1 = WR[(k4*3 + 1)*64 + j];
                float4 w2 = WR[(k4*3 + 2)*64 + j];
                v2f rA0; rA0[0] = rr0.x; rA0[1] = rr0.y;
                v2f rB0; rB0[0] = rr0.z; rB0[1] = rr0.w;
                v2f rA1; rA1[0] = rr1.x; rA1[1] = rr1.y;
                v2f rB1; rB1[0] = rr1.z; rB1[1] = rr1.w;
                v2f t;
                t[0] = w0.x; t[1] = w0.y; r20 += rA0 * t; r21 += rA1 * t;
                t[0] = w0.z; t[1] = w0.w; r20 += rB0 * t; r21 += rB1 * t;
                t[0] = w1.x; t[1] = w1.y; z20 += rA0 * t; z21 += rA1 * t;
                t[0] = w1.z; t[1] = w1.w; z20 += rB0 * t; z21 += rB1 * t;
                t[0] = w2.x; t[1] = w2.y; n20 += rA0 * t; n21 += rA1 * t;
                t[0] = w2.z; t[1] = w2.w; n20 += rB0 * t; n21 += rB1 * t;
            }
            Rr0 = r20[0] + r20[1]; Rz0 = z20[0] + z20[1]; Rn0 = n20[0] + n20[1];
            Rr1 = r21[0] + r21[1]; Rz1 = z21[0] + z21[1]; Rn1 = n21[0] + n21[1];
        }

        // ---- 16 GRU steps, both chains, fully unrolled; G 1-step pipelined ----
        float cg0_0, cg1_0, cg2_0, cg0_1, cg1_1, cg2_1;
        {
            const float* Gp0 = G + toks0[0]*192;
            const float* Gp1 = G + toks1[0]*192;
            cg0_0 = Gp0[j]; cg1_0 = Gp0[64 + j]; cg2_0 = Gp0[128 + j];
            cg0_1 = Gp1[j]; cg1_1 = Gp1[64 + j]; cg2_1 = Gp1[128 + j];
        }
#pragma unroll
        for (int t = 0; t < F_; ++t) {
            float ng0_0 = 0.f, ng1_0 = 0.f, ng2_0 = 0.f;
            float ng0_1 = 0.f, ng1_1 = 0.f, ng2_1 = 0.f;
            if (t + 1 < F_) {
                const float* Gn0 = G + toks0[t + 1]*192;
                const float* Gn1 = G + toks1[t + 1]*192;
                ng0_0 = Gn0[j]; ng1_0 = Gn0[64 + j]; ng2_0 = Gn0[128 + j];
                ng0_1 = Gn1[j]; ng1_1 = Gn1[64 + j]; ng2_1 = Gn1[128 + j];
            }
            v2f ar0 = {bhr, 0.f}, az0 = {bhz, 0.f}, an0 = {bhn, 0.f};
            v2f ar1 = {bhr, 0.f}, az1 = {bhz, 0.f}, an1 = {bhn, 0.f};
            v2f br0 = {0.f,0.f}, bz0 = {0.f,0.f}, bn0 = {0.f,0.f};
            v2f br1 = {0.f,0.f}, bz1 = {0.f,0.f}, bn1 = {0.f,0.f};
#pragma unroll
            for (int k4 = 0; k4 < 16; ++k4) {
                float4 hh0 = h4_0[k4];
                float4 hh1 = h4_1[k4];
                v2f h0A; h0A[0] = hh0.x; h0A[1] = hh0.y;
                v2f h0B; h0B[0] = hh0.z; h0B[1] = hh0.w;
                v2f h1A; h1A[0] = hh1.x; h1A[1] = hh1.y;
                v2f h1B; h1B[0] = hh1.z; h1B[1] = hh1.w;
                ar0 += h0A * wrv[2*k4]; br0 += h0B * wrv[2*k4+1];
                az0 += h0A * wzv[2*k4]; bz0 += h0B * wzv[2*k4+1];
                an0 += h0A * wnv[2*k4]; bn0 += h0B * wnv[2*k4+1];
                ar1 += h1A * wrv[2*k4]; br1 += h1B * wrv[2*k4+1];
                az1 += h1A * wzv[2*k4]; bz1 += h1B * wzv[2*k4+1];
                an1 += h1A * wnv[2*k4]; bn1 += h1B * wnv[2*k4+1];
            }
            float ghr0 = (ar0[0] + br0[0]) + (ar0[1] + br0[1]);
            float ghz0 = (az0[0] + bz0[0]) + (az0[1] + bz0[1]);
            float ghn0 = (an0[0] + bn0[0]) + (an0[1] + bn0[1]);
            float ghr1 = (ar1[0] + br1[0]) + (ar1[1] + br1[1]);
            float ghz1 = (az1[0] + bz1[0]) + (az1[1] + bz1[1]);
            float ghn1 = (an1[0] + bn1[0]) + (an1[1] + bn1[1]);
            float r0 = sigm((cg0_0 + Rr0) + ghr0);
            float z0 = sigm((cg1_0 + Rz0) + ghz0);
            float n0 = tanh_f((cg2_0 + Rn0) + r0 * ghn0);
            float r1 = sigm((cg0_1 + Rr1) + ghr1);
            float z1 = sigm((cg1_1 + Rz1) + ghz1);
            float n1 = tanh_f((cg2_1 + Rn1) + r1 * ghn1);
            h0 = (1.f - z0) * n0 + z0 * h0;
            h1 = (1.f - z1) * n1 + z1 * h1;
            __builtin_amdgcn_wave_barrier();
            h0_s[j] = h0;
            h1_s[j] = h1;
            __builtin_amdgcn_wave_barrier();
            cg0_0 = ng0_0; cg1_0 = ng1_0; cg2_0 = ng2_0;
            cg0_1 = ng0_1; cg1_1 = ng1_1; cg2_1 = ng2_1;
        }
    }

    // ---- head: out[b][j] = h @ head_w[j] + head_b[j] (both chains) ----
    float o0 = head_b[j], o1 = head_b[j];
#pragma unroll 8
    for (int k = 0; k < 64; ++k) {
        float w = head_w[j*64 + k];
        o0 += h0_s[k] * w;
        o1 += h1_s[k] * w;
    }
    out[(size_t)b0*64 + j] = o0;
    out[(size_t)b1*64 + j] = o1;
}

extern "C" void kernel_launch(void* const* d_in, const int* in_sizes, int n_in,
                              void* d_out, int out_size, void* d_ws, size_t ws_size,
                              hipStream_t stream) {
    const int*   seq      = (const int*)  d_in[0];
    const float* memory   = (const float*)d_in[1];
    const float* embed_w  = (const float*)d_in[2];
    const float* w_ih     = (const float*)d_in[3];
    const float* w_hh     = (const float*)d_in[4];
    const float* b_ih     = (const float*)d_in[5];
    const float* b_hh     = (const float*)d_in[6];
    const float* key_w    = (const float*)d_in[7];
    const float* key_b    = (const float*)d_in[8];
    const float* val_w    = (const float*)d_in[9];
    const float* val_b    = (const float*)d_in[10];
    const float* query_w  = (const float*)d_in[11];
    const float* query_b  = (const float*)d_in[12];
    const float* head_w   = (const float*)d_in[13];
    const float* head_b   = (const float*)d_in[14];

    char* ws = (char*)d_ws;
    __half* kT_h  = (__half*)(ws + WS_KT);
    __half* v_h   = (__half*)(ws + WS_V);
    float*  G     = (float*) (ws + WS_G);
    float4* WPhh  = (float4*)(ws + WS_WPHH);
    float4* WR    = (float4*)(ws + WS_WR);
    __half2* QPh  = (__half2*)(ws + WS_QP);
    float4* KWP   = (float4*)(ws + WS_KWP);
    float4* VWP   = (float4*)(ws + WS_VWP);

    (void)hipFuncSetAttribute((const void*)recurrent_main,
                              hipFuncAttributeMaxDynamicSharedMemorySize,
                              (int)SMEM_BYTES);

    pack_weights<<<36, 256, 0, stream>>>(w_ih, w_hh, query_w, key_w, val_w,
                                         WPhh, WR, QPh, KWP, VWP);
    build_G<<<64, 64, 0, stream>>>(embed_w, w_ih, b_ih, G);
    compute_kv<<<(B_*M_)/4, 256, 0, stream>>>(memory, key_b, val_b, KWP, VWP, kT_h, v_h);
    recurrent_main<<<B_/2, 64, SMEM_BYTES, stream>>>(seq, b_hh, query_b, head_w, head_b,
                                                     kT_h, v_h, G, WPhh, WR, (float*)d_out);
}

// Round 8
// 2970.956 us; speedup vs baseline: 2.2905x; 2.2905x over previous
//
#include <hip/hip_runtime.h>
#include <hip/hip_fp16.h>

// FixedFreqModel: B=512, L=2048, M=256, H=64, VOCAB=64, READ_FREQ=16.
// R8: revert to R6 structure (1 wave/batch, 512 blocks, fp16 kT/v/QP in
// 75.5KB LDS, 2 blocks/CU, W_hh in 192 VGPRs, packed-fp32 math), then:
//  - GRU: dynamic loop over 4 groups x 4 unrolled steps (code ~4x smaller
//    than R6's full unroll -> fits I-cache); tokens+G pipelined one GROUP
//    ahead in 16 NAMED registers (static indices, no scratch arrays).
//  - softmax: no max-subtraction (|s|<=~6, exp safe) + rcp instead of div;
//    sigmoid/tanh via v_rcp. Removes ~6 serial shuffles + div chains.
// R7 lesson: two chains per wave spills (weights 192 + 2x state > 256 VGPR)
// and v-from-global refetches 1.5GB; both reverted.

#define B_ 512
#define L_ 2048
#define M_ 256
#define H_ 64
#define C_ 128
#define F_ 16

typedef float v2f __attribute__((ext_vector_type(2)));

// workspace offsets (bytes)
#define WS_KT    0u            // 512*16384 halves = 16 MB
#define WS_V     16777216u     // 16 MB
#define WS_G     33554432u     // 64*192 fp32 = 48 KB
#define WS_WPHH  33603584u     // 3072 float4 = 48 KB
#define WS_WR    33652736u     // 3072 float4 = 48 KB
#define WS_QP    33701888u     // 1024 * 8B (half4) = 8 KB
#define WS_KWP   33710080u     // 1024 float4 = 16 KB
#define WS_VWP   33726464u     // 16 KB

// dynamic LDS layout (bytes)
#define S_KT   0u        // 32768 : kT half [hh][m]   (64 x 256)
#define S_V    32768u    // 32768 : v  half [m][h]    (256 x 64)
#define S_QP   65536u    // 8192  : QP half4 [k4][j]  (16 x 64)
#define S_P    73728u    // 1024  : float4 p_s[64]
#define S_H    74752u    // 256   : h fp32
#define S_RET  75008u    // 256
#define S_Q    75264u    // 256
#define SMEM_BYTES 75520u

__device__ __forceinline__ float dot4(float4 a, float4 b) {
    return a.x*b.x + a.y*b.y + a.z*b.z + a.w*b.w;
}
__device__ __forceinline__ void cvt2v(uint2 raw, v2f& lo, v2f& hi) {
    __half2* hp = (__half2*)&raw;
    float2 a = __half22float2(hp[0]);
    float2 b = __half22float2(hp[1]);
    lo[0] = a.x; lo[1] = a.y; hi[0] = b.x; hi[1] = b.y;
}
__device__ __forceinline__ float fast_rcp(float x) { return __builtin_amdgcn_rcpf(x); }
__device__ __forceinline__ float sigm(float x) { return fast_rcp(1.f + __expf(-x)); }
__device__ __forceinline__ float tanh_f(float x) {
    float e2 = __expf(-2.f * fabsf(x));
    return copysignf((1.f - e2) * fast_rcp(1.f + e2), x);
}

// ---------------- pack weights -----------------------------------------------
__global__ void pack_weights(const float* __restrict__ w_ih,
                             const float* __restrict__ w_hh,
                             const float* __restrict__ qw,
                             const float* __restrict__ kw,
                             const float* __restrict__ vw,
                             float4* __restrict__ WPhh,
                             float4* __restrict__ WR,
                             __half2* __restrict__ QPh,
                             float4* __restrict__ KWP,
                             float4* __restrict__ VWP)
{
    int idx = blockIdx.x * 256 + threadIdx.x;
    if (idx < 3072) {                       // WPhh[(k4*3+g)*64+j] = w_hh[(g*64+j)][4k4..]
        int j = idx & 63, kg = idx >> 6, g = kg % 3, k4 = kg / 3;
        const float* s = w_hh + (g*64 + j)*64 + 4*k4;
        WPhh[idx] = make_float4(s[0], s[1], s[2], s[3]);
    } else if (idx < 6144) {                // WR: retrieved half of w_ih (cols 64..127)
        int i = idx - 3072;
        int j = i & 63, kg = i >> 6, g = kg % 3, k4 = kg / 3;
        const float* s = w_ih + (g*64 + j)*128 + 64 + 4*k4;
        WR[i] = make_float4(s[0], s[1], s[2], s[3]);
    } else if (idx < 7168) {                // QPh: half4 of qw[j][4k4..]
        int i = idx - 6144;
        int j = i & 63, k4 = i >> 6;
        const float* s = qw + j*64 + 4*k4;
        QPh[i*2]     = __floats2half2_rn(s[0], s[1]);
        QPh[i*2 + 1] = __floats2half2_rn(s[2], s[3]);
    } else if (idx < 8192) {
        int i = idx - 7168;
        int j = i & 63, k4 = i >> 6;
        const float* s = kw + j*64 + 4*k4;
        KWP[i] = make_float4(s[0], s[1], s[2], s[3]);
    } else if (idx < 9216) {
        int i = idx - 8192;
        int j = i & 63, k4 = i >> 6;
        const float* s = vw + j*64 + 4*k4;
        VWP[i] = make_float4(s[0], s[1], s[2], s[3]);
    }
}

// ---------------- G[v][o] = sum_k embed[v][k]*w_ih[o][k] + b_ih[o] ----------
__global__ __launch_bounds__(64) void build_G(const float* __restrict__ embed_w,
                                              const float* __restrict__ w_ih,
                                              const float* __restrict__ b_ih,
                                              float* __restrict__ G)
{
    int v = blockIdx.x, j = threadIdx.x;
    __shared__ float e_s[64];
    e_s[j] = embed_w[v*64 + j];
    __syncthreads();
    float a0 = b_ih[j], a1 = b_ih[64 + j], a2 = b_ih[128 + j];
    for (int k = 0; k < 64; ++k) {
        float e = e_s[k];
        a0 += e * w_ih[j*128 + k];
        a1 += e * w_ih[(64 + j)*128 + k];
        a2 += e * w_ih[(128 + j)*128 + k];
    }
    G[v*192 + j]       = a0;
    G[v*192 + 64 + j]  = a1;
    G[v*192 + 128 + j] = a2;
}

// ---------------- k/v precompute (fp16 outputs) ------------------------------
__global__ __launch_bounds__(256) void compute_kv(const float* __restrict__ memory,
                                                  const float* __restrict__ key_b,
                                                  const float* __restrict__ val_b,
                                                  const float4* __restrict__ KWP,
                                                  const float4* __restrict__ VWP,
                                                  __half* __restrict__ kT_h,
                                                  __half* __restrict__ v_h)
{
    int wid = threadIdx.x >> 6;
    int o   = threadIdx.x & 63;
    int row = blockIdx.x * 4 + wid;          // row = b*256 + m
    int b = row >> 8, m = row & 255;
    __shared__ __align__(16) float mem_s[4][64];
    mem_s[wid][o] = memory[(size_t)row * 64 + o];
    __syncthreads();
    float ak = key_b[o], av = val_b[o];
    const float4* m4 = (const float4*)mem_s[wid];
#pragma unroll
    for (int k4 = 0; k4 < 16; ++k4) {
        float4 mm = m4[k4];
        ak += dot4(mm, KWP[k4*64 + o]);
        av += dot4(mm, VWP[k4*64 + o]);
    }
    kT_h[((size_t)b*64 + o)*256 + m] = __float2half(ak);  // scattered, one-time
    v_h[(size_t)row*64 + o]          = __float2half(av);  // coalesced
}

// one GRU step: uses named cg0/cg1/cg2 (G row for this token)
#define GRU_STEP(cg0, cg1, cg2) do {                                        \
    v2f ar0 = {bhr, 0.f}, az0 = {bhz, 0.f}, an0 = {bhn, 0.f};               \
    v2f br0 = {0.f,0.f}, bz0 = {0.f,0.f}, bn0 = {0.f,0.f};                  \
    _Pragma("unroll")                                                       \
    for (int k4 = 0; k4 < 16; ++k4) {                                       \
        float4 hh = h4[k4];                                                 \
        v2f hA; hA[0] = hh.x; hA[1] = hh.y;                                 \
        v2f hB; hB[0] = hh.z; hB[1] = hh.w;                                 \
        ar0 += hA * wrv[2*k4]; br0 += hB * wrv[2*k4+1];                     \
        az0 += hA * wzv[2*k4]; bz0 += hB * wzv[2*k4+1];                     \
        an0 += hA * wnv[2*k4]; bn0 += hB * wnv[2*k4+1];                     \
    }                                                                       \
    float ghr = (ar0[0] + br0[0]) + (ar0[1] + br0[1]);                      \
    float ghz = (az0[0] + bz0[0]) + (az0[1] + bz0[1]);                      \
    float ghn = (an0[0] + bn0[0]) + (an0[1] + bn0[1]);                      \
    float r_ = sigm((cg0 + Rr) + ghr);                                      \
    float z_ = sigm((cg1 + Rz) + ghz);                                      \
    float n_ = tanh_f((cg2 + Rn) + r_ * ghn);                               \
    h = (1.f - z_) * n_ + z_ * h;                                           \
    __builtin_amdgcn_wave_barrier();                                        \
    h_s[j] = h;                                                             \
    __builtin_amdgcn_wave_barrier();                                        \
} while (0)

// ---------------- main recurrent kernel: 1 wave per batch element ------------
__global__ __launch_bounds__(64, 1) void recurrent_main(
    const int*   __restrict__ seq,
    const float* __restrict__ b_hh,
    const float* __restrict__ query_b,
    const float* __restrict__ head_w,
    const float* __restrict__ head_b,
    const __half* __restrict__ kT_h,
    const __half* __restrict__ v_h,
    const float* __restrict__ G,
    const float4* __restrict__ WPhh,
    const float4* __restrict__ WR,
    float* __restrict__ out)
{
    const int b = blockIdx.x;
    const int j = threadIdx.x;

    extern __shared__ __align__(16) char smem[];
    const uint2* kT_u2 = (const uint2*)(smem + S_KT);   // [hh*64 + j]  (j = m-quad)
    const uint2* v_u2  = (const uint2*)(smem + S_V);    // [m*16 + o4]
    const uint2* qp_u2 = (const uint2*)(smem + S_QP);   // [k4*64 + j]
    float4* p_s4  = (float4*)(smem + S_P);
    float*  h_s   = (float*)(smem + S_H);
    float*  ret_s = (float*)(smem + S_RET);
    float*  q_s   = (float*)(smem + S_Q);

    // ---- stage kT, v (fp16) and QP into LDS once ----
    {
        const uint4* kTg = (const uint4*)(kT_h + (size_t)b * 16384);
        const uint4* vg  = (const uint4*)(v_h  + (size_t)b * 16384);
        uint4* kTls = (uint4*)(smem + S_KT);
        uint4* vls  = (uint4*)(smem + S_V);
#pragma unroll
        for (int i = 0; i < 32; ++i) {
            kTls[i*64 + j] = kTg[i*64 + j];
            vls[i*64 + j]  = vg[i*64 + j];
        }
        const uint4* qpg = (const uint4*)((const char*)WPhh + (WS_QP - WS_WPHH));
        uint4* qls = (uint4*)(smem + S_QP);
#pragma unroll
        for (int i = 0; i < 8; ++i) qls[i*64 + j] = qpg[i*64 + j];
    }

    // ---- W_hh permanently in registers as v2f pairs: 96 v2f = 192 VGPRs ----
    v2f wrv[32], wzv[32], wnv[32];
#pragma unroll
    for (int k4 = 0; k4 < 16; ++k4) {
        float4 a = WPhh[(k4*3 + 0)*64 + j];
        float4 bq = WPhh[(k4*3 + 1)*64 + j];
        float4 cq = WPhh[(k4*3 + 2)*64 + j];
        wrv[2*k4][0] = a.x;  wrv[2*k4][1] = a.y;
        wrv[2*k4+1][0] = a.z; wrv[2*k4+1][1] = a.w;
        wzv[2*k4][0] = bq.x; wzv[2*k4][1] = bq.y;
        wzv[2*k4+1][0] = bq.z; wzv[2*k4+1][1] = bq.w;
        wnv[2*k4][0] = cq.x; wnv[2*k4][1] = cq.y;
        wnv[2*k4+1][0] = cq.z; wnv[2*k4+1][1] = cq.w;
    }

    float h = 0.f;
    h_s[j] = 0.f;
    const float bhr = b_hh[j], bhz = b_hh[64 + j], bhn = b_hh[128 + j];
    const float qb  = query_b[j];
    __builtin_amdgcn_wave_barrier();

    const int*    seqb = seq + (size_t)b * L_;
    const float4* h4   = (const float4*)h_s;
    const float4* r4   = (const float4*)ret_s;
    const float4* q_sf4 = (const float4*)q_s;

    const int o4 = j & 15;        // h-quad owned in v-loop
    const int mg = j >> 4;        // m-group 0..3

    for (int c = 0; c < C_; ++c) {
        const int c16 = c * F_;
        // ---- group-0 tokens + G rows: issue early, consumed after attention ----
        int ta = seqb[c16 + 0], tb = seqb[c16 + 1], tc = seqb[c16 + 2], td = seqb[c16 + 3];
        float cA0, cA1, cA2, cB0, cB1, cB2, cC0, cC1, cC2, cD0, cD1, cD2;
        {
            const float* GA = G + ta*192; cA0 = GA[j]; cA1 = GA[64+j]; cA2 = GA[128+j];
            const float* GB = G + tb*192; cB0 = GB[j]; cB1 = GB[64+j]; cB2 = GB[128+j];
            const float* GC = G + tc*192; cC0 = GC[j]; cC1 = GC[64+j]; cC2 = GC[128+j];
            const float* GD = G + td*192; cD0 = GD[j]; cD1 = GD[64+j]; cD2 = GD[128+j];
        }

        // ---- q = h @ Wq^T + qb  (QP fp16 from LDS, packed fma) ----
        {
            v2f qa = {qb, 0.f}, qc = {0.f, 0.f};
#pragma unroll
            for (int k4 = 0; k4 < 16; ++k4) {
                float4 hh = h4[k4];
                v2f hA; hA[0] = hh.x; hA[1] = hh.y;
                v2f hB; hB[0] = hh.z; hB[1] = hh.w;
                v2f plo, phi; cvt2v(qp_u2[k4*64 + j], plo, phi);
                qa += hA * plo;
                qc += hB * phi;
            }
            q_s[j] = (qa[0] + qc[0]) + (qa[1] + qc[1]);
        }
        __builtin_amdgcn_wave_barrier();

        // ---- scores: lane j owns m = 4j..4j+3 (fp16 kT, packed) ----
        v2f s01a = {0.f,0.f}, s23a = {0.f,0.f};
        v2f s01b = {0.f,0.f}, s23b = {0.f,0.f};
#pragma unroll 4
        for (int hq = 0; hq < 16; ++hq) {
            float4 qq = q_sf4[hq];
            v2f k0l,k0h,k1l,k1h,k2l,k2h,k3l,k3h;
            cvt2v(kT_u2[(4*hq+0)*64 + j], k0l, k0h);
            cvt2v(kT_u2[(4*hq+1)*64 + j], k1l, k1h);
            cvt2v(kT_u2[(4*hq+2)*64 + j], k2l, k2h);
            cvt2v(kT_u2[(4*hq+3)*64 + j], k3l, k3h);
            s01a += k0l * qq.x; s23a += k0h * qq.x;
            s01b += k1l * qq.y; s23b += k1h * qq.y;
            s01a += k2l * qq.z; s23a += k2h * qq.z;
            s01b += k3l * qq.w; s23b += k3h * qq.w;
        }
        const float scale = 0.125f;
        // ---- softmax (no max-sub: |s| small, exp safe; rcp not div) ----
        float4 p;
        p.x = __expf((s01a[0] + s01b[0]) * scale);
        p.y = __expf((s01a[1] + s01b[1]) * scale);
        p.z = __expf((s23a[0] + s23b[0]) * scale);
        p.w = __expf((s23a[1] + s23b[1]) * scale);
        float sum = (p.x + p.y) + (p.z + p.w);
#pragma unroll
        for (int o = 32; o > 0; o >>= 1) sum += __shfl_xor(sum, o);
        float inv = fast_rcp(sum);
        p_s4[j] = p;
        __builtin_amdgcn_wave_barrier();

        // ---- retrieved: lane (mg,o4) over m = 4i+mg (fp16 v, packed) ----
        const float* ps = (const float*)p_s4;
        v2f aA0 = {0.f,0.f}, aB0 = {0.f,0.f};
        v2f aA1 = {0.f,0.f}, aB1 = {0.f,0.f};
#pragma unroll 8
        for (int i = 0; i < 64; i += 2) {
            int m0 = 4*i + mg, m1 = 4*(i + 1) + mg;
            float p0 = ps[m0], p1 = ps[m1];
            v2f v0l, v0h, v1l, v1h;
            cvt2v(v_u2[m0*16 + o4], v0l, v0h);
            cvt2v(v_u2[m1*16 + o4], v1l, v1h);
            aA0 += v0l * p0; aB0 += v0h * p0;
            aA1 += v1l * p1; aB1 += v1h * p1;
        }
        float4 acc;
        acc.x = (aA0[0] + aA1[0]) * inv;
        acc.y = (aA0[1] + aA1[1]) * inv;
        acc.z = (aB0[0] + aB1[0]) * inv;
        acc.w = (aB0[1] + aB1[1]) * inv;
#pragma unroll
        for (int o = 16; o <= 32; o <<= 1) {
            acc.x += __shfl_xor(acc.x, o);
            acc.y += __shfl_xor(acc.y, o);
            acc.z += __shfl_xor(acc.z, o);
            acc.w += __shfl_xor(acc.w, o);
        }
        if (j < 16) ((float4*)ret_s)[j] = acc;
        __builtin_amdgcn_wave_barrier();

        // ---- R = W_r @ ret (chunk-constant; WR from global, packed) ----
        float Rr, Rz, Rn;
        {
            v2f r2 = {0.f,0.f}, z2 = {0.f,0.f}, n2 = {0.f,0.f};
#pragma unroll
            for (int k4 = 0; k4 < 16; ++k4) {
                float4 rr = r4[k4];
                v2f rA; rA[0] = rr.x; rA[1] = rr.y;
                v2f rB; rB[0] = rr.z; rB[1] = rr.w;
                float4 w0 = WR[(k4*3 + 0)*64 + j];
                float4 w1 = WR[(k4*3 + 1)*64 + j];
                float4 w2 = WR[(k4*3 + 2)*64 + j];
                v2f t;
                t[0] = w0.x; t[1] = w0.y; r2 += rA * t;
                t[0] = w0.z; t[1] = w0.w; r2 += rB * t;
                t[0] = w1.x; t[1] = w1.y; z2 += rA * t;
                t[0] = w1.z; t[1] = w1.w; z2 += rB * t;
                t[0] = w2.x; t[1] = w2.y; n2 += rA * t;
                t[0] = w2.z; t[1] = w2.w; n2 += rB * t;
            }
            Rr = r2[0] + r2[1]; Rz = z2[0] + z2[1]; Rn = n2[0] + n2[1];
        }

        // ---- 16 GRU steps: 4 groups x 4 unrolled; tokens+G one GROUP ahead
        //      in NAMED registers (static indices -> no scratch) ----
#pragma unroll 1
        for (int g = 0; g < 4; ++g) {
            int nbase = c16 + (((g + 1) & 3) << 2);   // wraps at g=3 (dummy, in-bounds)
            int na = seqb[nbase + 0], nb = seqb[nbase + 1];
            int nc = seqb[nbase + 2], nd = seqb[nbase + 3];
            const float* NA = G + na*192;
            const float* NB = G + nb*192;
            const float* NC = G + nc*192;
            const float* ND = G + nd*192;
            float nA0 = NA[j], nA1 = NA[64+j], nA2 = NA[128+j];
            float nB0 = NB[j], nB1 = NB[64+j], nB2 = NB[128+j];
            float nC0 = NC[j], nC1 = NC[64+j], nC2 = NC[128+j];
            float nD0 = ND[j], nD1 = ND[64+j], nD2 = ND[128+j];

            GRU_STEP(cA0, cA1, cA2);
            GRU_STEP(cB0, cB1, cB2);
            GRU_STEP(cC0, cC1, cC2);
            GRU_STEP(cD0, cD1, cD2);

            cA0 = nA0; cA1 = nA1; cA2 = nA2;
            cB0 = nB0; cB1 = nB1; cB2 = nB2;
            cC0 = nC0; cC1 = nC1; cC2 = nC2;
            cD0 = nD0; cD1 = nD1; cD2 = nD2;
        }
    }

    // ---- head: out[b][j] = h @ head_w[j] + head_b[j] ----
    float o = head_b[j];
#pragma unroll 8
    for (int k = 0; k < 64; ++k)
        o += h_s[k] * head_w[j*64 + k];
    out[(size_t)b*64 + j] = o;
}

extern "C" void kernel_launch(void* const* d_in, const int* in_sizes, int n_in,
                              void* d_out, int out_size, void* d_ws, size_t ws_size,
                              hipStream_t stream) {
    const int*   seq      = (const int*)  d_in[0];
    const float* memory   = (const float*)d_in[1];
    const float* embed_w  = (const float*)d_in[2];
    const float* w_ih     = (const float*)d_in[3];
    const float* w_hh     = (const float*)d_in[4];
    const float* b_ih     = (const float*)d_in[5];
    const float* b_hh     = (const float*)d_in[6];
    const float* key_w    = (const float*)d_in[7];
    const float* key_b    = (const float*)d_in[8];
    const float* val_w    = (const float*)d_in[9];
    const float* val_b    = (const float*)d_in[10];
    const float* query_w  = (const float*)d_in[11];
    const float* query_b  = (const float*)d_in[12];
    const float* head_w   = (const float*)d_in[13];
    const float* head_b   = (const float*)d_in[14];

    char* ws = (char*)d_ws;
    __half* kT_h  = (__half*)(ws + WS_KT);
    __half* v_h   = (__half*)(ws + WS_V);
    float*  G     = (float*) (ws + WS_G);
    float4* WPhh  = (float4*)(ws + WS_WPHH);
    float4* WR    = (float4*)(ws + WS_WR);
    __half2* QPh  = (__half2*)(ws + WS_QP);
    float4* KWP   = (float4*)(ws + WS_KWP);
    float4* VWP   = (float4*)(ws + WS_VWP);

    (void)hipFuncSetAttribute((const void*)recurrent_main,
                              hipFuncAttributeMaxDynamicSharedMemorySize,
                              (int)SMEM_BYTES);

    pack_weights<<<36, 256, 0, stream>>>(w_ih, w_hh, query_w, key_w, val_w,
                                         WPhh, WR, QPh, KWP, VWP);
    build_G<<<64, 64, 0, stream>>>(embed_w, w_ih, b_ih, G);
    compute_kv<<<(B_*M_)/4, 256, 0, stream>>>(memory, key_b, val_b, KWP, VWP, kT_h, v_h);
    recurrent_main<<<B_, 64, SMEM_BYTES, stream>>>(seq, b_hh, query_b, head_w, head_b,
                                                   kT_h, v_h, G, WPhh, WR, (float*)d_out);
}

// Round 9
// 2466.787 us; speedup vs baseline: 2.7587x; 1.2044x over previous
//
#include <hip/hip_runtime.h>
#include <hip/hip_fp16.h>

// FixedFreqModel: B=512, L=2048, M=256, H=64, VOCAB=64, READ_FREQ=16.
// R9: R6 base (1 wave/batch, 512 blocks, fp16 kT/v in LDS, W_hh in 192 VGPRs)
// with ALL h/ret/q broadcasts switched from LDS round-trips to v_readlane:
//  - GRU: h stays in lane j's register; matvec uses readlane(h,k) broadcast.
//    Zero LDS, zero barriers in the 16-step loop (was 256 dependent
//    ds_read_b128 + 32 barriers per chunk = the ~43k cyc stall, R8 analysis).
//  - q matvec, scores q-broadcast, R matvec: same readlane treatment.
//  - LDS keeps only kT/v/QP (static-address, batchable) + p.
// Weights packed as v2f (r,z) pairs + scalar n: per k = readlane + pk_fma + fmac.

#define B_ 512
#define L_ 2048
#define M_ 256
#define H_ 64
#define C_ 128
#define F_ 16

typedef float v2f __attribute__((ext_vector_type(2)));

// workspace offsets (bytes)
#define WS_KT    0u            // 512*16384 halves = 16 MB
#define WS_V     16777216u     // 16 MB
#define WS_G     33554432u     // 64*192 fp32 = 48 KB
#define WS_WPHH  33603584u     // 3072 float4 = 48 KB
#define WS_WR    33652736u     // 3072 float4 = 48 KB
#define WS_QP    33701888u     // 1024 * 8B (half4) = 8 KB
#define WS_KWP   33710080u     // 1024 float4 = 16 KB
#define WS_VWP   33726464u     // 16 KB

// dynamic LDS layout (bytes)
#define S_KT   0u        // 32768 : kT half [hh][m]   (64 x 256)
#define S_V    32768u    // 32768 : v  half [m][h]    (256 x 64)
#define S_QP   65536u    // 8192  : QP half4 [k4][j]  (16 x 64)
#define S_P    73728u    // 1024  : float4 p_s[64]
#define SMEM_BYTES 74752u

__device__ __forceinline__ float dot4(float4 a, float4 b) {
    return a.x*b.x + a.y*b.y + a.z*b.z + a.w*b.w;
}
__device__ __forceinline__ void cvt2v(uint2 raw, v2f& lo, v2f& hi) {
    __half2* hp = (__half2*)&raw;
    float2 a = __half22float2(hp[0]);
    float2 b = __half22float2(hp[1]);
    lo[0] = a.x; lo[1] = a.y; hi[0] = b.x; hi[1] = b.y;
}
__device__ __forceinline__ float fast_rcp(float x) { return __builtin_amdgcn_rcpf(x); }
__device__ __forceinline__ float sigm(float x) { return fast_rcp(1.f + __expf(-x)); }
__device__ __forceinline__ float tanh_f(float x) {
    float e2 = __expf(-2.f * fabsf(x));
    return copysignf((1.f - e2) * fast_rcp(1.f + e2), x);
}
// lane broadcast without LDS: 2-cyc VALU, no latency
__device__ __forceinline__ float rl(float v, int lane) {
    return __int_as_float(__builtin_amdgcn_readlane(__float_as_int(v), lane));
}

// ---------------- pack weights -----------------------------------------------
__global__ void pack_weights(const float* __restrict__ w_ih,
                             const float* __restrict__ w_hh,
                             const float* __restrict__ qw,
                             const float* __restrict__ kw,
                             const float* __restrict__ vw,
                             float4* __restrict__ WPhh,
                             float4* __restrict__ WR,
                             __half2* __restrict__ QPh,
                             float4* __restrict__ KWP,
                             float4* __restrict__ VWP)
{
    int idx = blockIdx.x * 256 + threadIdx.x;
    if (idx < 3072) {                       // WPhh[(k4*3+g)*64+j] = w_hh[(g*64+j)][4k4..]
        int j = idx & 63, kg = idx >> 6, g = kg % 3, k4 = kg / 3;
        const float* s = w_hh + (g*64 + j)*64 + 4*k4;
        WPhh[idx] = make_float4(s[0], s[1], s[2], s[3]);
    } else if (idx < 6144) {                // WR: retrieved half of w_ih (cols 64..127)
        int i = idx - 3072;
        int j = i & 63, kg = i >> 6, g = kg % 3, k4 = kg / 3;
        const float* s = w_ih + (g*64 + j)*128 + 64 + 4*k4;
        WR[i] = make_float4(s[0], s[1], s[2], s[3]);
    } else if (idx < 7168) {                // QPh: half4 of qw[j][4k4..]
        int i = idx - 6144;
        int j = i & 63, k4 = i >> 6;
        const float* s = qw + j*64 + 4*k4;
        QPh[i*2]     = __floats2half2_rn(s[0], s[1]);
        QPh[i*2 + 1] = __floats2half2_rn(s[2], s[3]);
    } else if (idx < 8192) {
        int i = idx - 7168;
        int j = i & 63, k4 = i >> 6;
        const float* s = kw + j*64 + 4*k4;
        KWP[i] = make_float4(s[0], s[1], s[2], s[3]);
    } else if (idx < 9216) {
        int i = idx - 8192;
        int j = i & 63, k4 = i >> 6;
        const float* s = vw + j*64 + 4*k4;
        VWP[i] = make_float4(s[0], s[1], s[2], s[3]);
    }
}

// ---------------- G[v][o] = sum_k embed[v][k]*w_ih[o][k] + b_ih[o] ----------
__global__ __launch_bounds__(64) void build_G(const float* __restrict__ embed_w,
                                              const float* __restrict__ w_ih,
                                              const float* __restrict__ b_ih,
                                              float* __restrict__ G)
{
    int v = blockIdx.x, j = threadIdx.x;
    __shared__ float e_s[64];
    e_s[j] = embed_w[v*64 + j];
    __syncthreads();
    float a0 = b_ih[j], a1 = b_ih[64 + j], a2 = b_ih[128 + j];
    for (int k = 0; k < 64; ++k) {
        float e = e_s[k];
        a0 += e * w_ih[j*128 + k];
        a1 += e * w_ih[(64 + j)*128 + k];
        a2 += e * w_ih[(128 + j)*128 + k];
    }
    G[v*192 + j]       = a0;
    G[v*192 + 64 + j]  = a1;
    G[v*192 + 128 + j] = a2;
}

// ---------------- k/v precompute (fp16 outputs) ------------------------------
__global__ __launch_bounds__(256) void compute_kv(const float* __restrict__ memory,
                                                  const float* __restrict__ key_b,
                                                  const float* __restrict__ val_b,
                                                  const float4* __restrict__ KWP,
                                                  const float4* __restrict__ VWP,
                                                  __half* __restrict__ kT_h,
                                                  __half* __restrict__ v_h)
{
    int wid = threadIdx.x >> 6;
    int o   = threadIdx.x & 63;
    int row = blockIdx.x * 4 + wid;          // row = b*256 + m
    int b = row >> 8, m = row & 255;
    __shared__ __align__(16) float mem_s[4][64];
    mem_s[wid][o] = memory[(size_t)row * 64 + o];
    __syncthreads();
    float ak = key_b[o], av = val_b[o];
    const float4* m4 = (const float4*)mem_s[wid];
#pragma unroll
    for (int k4 = 0; k4 < 16; ++k4) {
        float4 mm = m4[k4];
        ak += dot4(mm, KWP[k4*64 + o]);
        av += dot4(mm, VWP[k4*64 + o]);
    }
    kT_h[((size_t)b*64 + o)*256 + m] = __float2half(ak);  // scattered, one-time
    v_h[(size_t)row*64 + o]          = __float2half(av);  // coalesced
}

// ---------------- main recurrent kernel: 1 wave per batch element ------------
__global__ __launch_bounds__(64, 1) void recurrent_main(
    const int*   __restrict__ seq,
    const float* __restrict__ b_hh,
    const float* __restrict__ query_b,
    const float* __restrict__ head_w,
    const float* __restrict__ head_b,
    const __half* __restrict__ kT_h,
    const __half* __restrict__ v_h,
    const float* __restrict__ G,
    const float4* __restrict__ WPhh,
    const float4* __restrict__ WR,
    float* __restrict__ out)
{
    const int b = blockIdx.x;
    const int j = threadIdx.x;

    extern __shared__ __align__(16) char smem[];
    const uint2* kT_u2 = (const uint2*)(smem + S_KT);   // [hh*64 + j]  (j = m-quad)
    const uint2* v_u2  = (const uint2*)(smem + S_V);    // [m*16 + o4]
    const uint2* qp_u2 = (const uint2*)(smem + S_QP);   // [k4*64 + j]
    float4* p_s4  = (float4*)(smem + S_P);

    // ---- stage kT, v (fp16) and QP into LDS once ----
    {
        const uint4* kTg = (const uint4*)(kT_h + (size_t)b * 16384);
        const uint4* vg  = (const uint4*)(v_h  + (size_t)b * 16384);
        uint4* kTls = (uint4*)(smem + S_KT);
        uint4* vls  = (uint4*)(smem + S_V);
#pragma unroll
        for (int i = 0; i < 32; ++i) {
            kTls[i*64 + j] = kTg[i*64 + j];
            vls[i*64 + j]  = vg[i*64 + j];
        }
        const uint4* qpg = (const uint4*)((const char*)WPhh + (WS_QP - WS_WPHH));
        uint4* qls = (uint4*)(smem + S_QP);
#pragma unroll
        for (int i = 0; i < 8; ++i) qls[i*64 + j] = qpg[i*64 + j];
    }

    // ---- W_hh permanently in registers: (r,z) as v2f pairs + n scalar ----
    // wrz[k] = {W_r[j][k], W_z[j][k]}, wn[k] = W_n[j][k]  -> 192 VGPRs
    v2f  wrz[64];
    float wn[64];
#pragma unroll
    for (int k4 = 0; k4 < 16; ++k4) {
        float4 a  = WPhh[(k4*3 + 0)*64 + j];
        float4 bq = WPhh[(k4*3 + 1)*64 + j];
        float4 cq = WPhh[(k4*3 + 2)*64 + j];
        wrz[4*k4+0][0] = a.x; wrz[4*k4+0][1] = bq.x; wn[4*k4+0] = cq.x;
        wrz[4*k4+1][0] = a.y; wrz[4*k4+1][1] = bq.y; wn[4*k4+1] = cq.y;
        wrz[4*k4+2][0] = a.z; wrz[4*k4+2][1] = bq.z; wn[4*k4+2] = cq.z;
        wrz[4*k4+3][0] = a.w; wrz[4*k4+3][1] = bq.w; wn[4*k4+3] = cq.w;
    }

    float h = 0.f;                       // lane j owns h[j]; never leaves regs
    const float bhr = b_hh[j], bhz = b_hh[64 + j], bhn = b_hh[128 + j];
    const float qb  = query_b[j];

    const int* seqb = seq + (size_t)b * L_;
    const int o4 = j & 15;        // h-quad owned in v-loop
    const int mg = j >> 4;        // m-group 0..3
    __builtin_amdgcn_wave_barrier();

    for (int c = 0; c < C_; ++c) {
        // ---- q[j] = qb + sum_k h[k] * Wq[j][k]  (h via readlane, QP LDS) ----
        float q = qb;
#pragma unroll
        for (int k4 = 0; k4 < 16; ++k4) {
            v2f plo, phi; cvt2v(qp_u2[k4*64 + j], plo, phi);
            float h0 = rl(h, 4*k4+0), h1 = rl(h, 4*k4+1);
            float h2 = rl(h, 4*k4+2), h3 = rl(h, 4*k4+3);
            q += h0*plo[0] + h1*plo[1] + h2*phi[0] + h3*phi[1];
        }

        // ---- scores: lane j owns m = 4j..4j+3; q broadcast via readlane ----
        v2f s01 = {0.f,0.f}, s23 = {0.f,0.f};
#pragma unroll 8
        for (int hh = 0; hh < 64; ++hh) {
            float qh = rl(q, hh);
            v2f kl, kh; cvt2v(kT_u2[hh*64 + j], kl, kh);
            s01 += kl * qh; s23 += kh * qh;
        }
        const float scale = 0.125f;
        // softmax, no max-sub (|s| small), rcp not div
        float4 p;
        p.x = __expf(s01[0]*scale); p.y = __expf(s01[1]*scale);
        p.z = __expf(s23[0]*scale); p.w = __expf(s23[1]*scale);
        float sum = (p.x + p.y) + (p.z + p.w);
#pragma unroll
        for (int o = 32; o > 0; o >>= 1) sum += __shfl_xor(sum, o);
        float inv = fast_rcp(sum);
        p_s4[j] = p;
        __builtin_amdgcn_wave_barrier();

        // ---- retrieved: lane (mg,o4) over m = 4i+mg (fp16 v, packed) ----
        const float* ps = (const float*)p_s4;
        v2f aA0 = {0.f,0.f}, aB0 = {0.f,0.f};
        v2f aA1 = {0.f,0.f}, aB1 = {0.f,0.f};
#pragma unroll 8
        for (int i = 0; i < 64; i += 2) {
            int m0 = 4*i + mg, m1 = 4*(i + 1) + mg;
            float p0 = ps[m0], p1 = ps[m1];
            v2f v0l, v0h, v1l, v1h;
            cvt2v(v_u2[m0*16 + o4], v0l, v0h);
            cvt2v(v_u2[m1*16 + o4], v1l, v1h);
            aA0 += v0l * p0; aB0 += v0h * p0;
            aA1 += v1l * p1; aB1 += v1h * p1;
        }
        float4 acc;
        acc.x = (aA0[0] + aA1[0]) * inv;
        acc.y = (aA0[1] + aA1[1]) * inv;
        acc.z = (aB0[0] + aB1[0]) * inv;
        acc.w = (aB0[1] + aB1[1]) * inv;
#pragma unroll
        for (int o = 16; o <= 32; o <<= 1) {
            acc.x += __shfl_xor(acc.x, o);
            acc.y += __shfl_xor(acc.y, o);
            acc.z += __shfl_xor(acc.z, o);
            acc.w += __shfl_xor(acc.w, o);
        }
        // now lane t (and t+16/32/48) holds ret[4t..4t+3] in acc

        // ---- R = W_r/z/n @ ret : ret broadcast via readlane, WR from global --
        v2f Rrz = {0.f,0.f}; float Rn = 0.f;
#pragma unroll
        for (int k4 = 0; k4 < 16; ++k4) {
            float4 w0 = WR[(k4*3 + 0)*64 + j];
            float4 w1 = WR[(k4*3 + 1)*64 + j];
            float4 w2 = WR[(k4*3 + 2)*64 + j];
            float r0 = rl(acc.x, k4), r1 = rl(acc.y, k4);
            float r2 = rl(acc.z, k4), r3 = rl(acc.w, k4);
            v2f t;
            t[0] = w0.x; t[1] = w1.x; Rrz += t * r0; Rn = fmaf(r0, w2.x, Rn);
            t[0] = w0.y; t[1] = w1.y; Rrz += t * r1; Rn = fmaf(r1, w2.y, Rn);
            t[0] = w0.z; t[1] = w1.z; Rrz += t * r2; Rn = fmaf(r2, w2.z, Rn);
            t[0] = w0.w; t[1] = w1.w; Rrz += t * r3; Rn = fmaf(r3, w2.w, Rn);
        }
        const float Rr = Rrz[0], Rz = Rrz[1];

        // ---- tokens (loaded after attention to cap register pressure) ----
        int toks[F_];
#pragma unroll
        for (int t = 0; t < F_; ++t) toks[t] = seqb[c*F_ + t];

        // ---- 16 GRU steps: PURE VALU. h broadcast via readlane; no LDS,
        //      no barriers. G rows pipelined one step ahead. ----
        float cg0, cg1, cg2;
        {
            const float* Gp = G + toks[0]*192;
            cg0 = Gp[j]; cg1 = Gp[64 + j]; cg2 = Gp[128 + j];
        }
#pragma unroll
        for (int t = 0; t < F_; ++t) {
            float ng0 = 0.f, ng1 = 0.f, ng2 = 0.f;
            if (t + 1 < F_) {
                const float* Gn = G + toks[t + 1]*192;
                ng0 = Gn[j]; ng1 = Gn[64 + j]; ng2 = Gn[128 + j];
            }
            v2f arz = {bhr, bhz};
            float an = bhn;
#pragma unroll
            for (int k4 = 0; k4 < 16; ++k4) {
                float h0 = rl(h, 4*k4+0), h1 = rl(h, 4*k4+1);
                float h2 = rl(h, 4*k4+2), h3 = rl(h, 4*k4+3);
                arz += wrz[4*k4+0] * h0; an = fmaf(h0, wn[4*k4+0], an);
                arz += wrz[4*k4+1] * h1; an = fmaf(h1, wn[4*k4+1], an);
                arz += wrz[4*k4+2] * h2; an = fmaf(h2, wn[4*k4+2], an);
                arz += wrz[4*k4+3] * h3; an = fmaf(h3, wn[4*k4+3], an);
            }
            float r_ = sigm((cg0 + Rr) + arz[0]);
            float z_ = sigm((cg1 + Rz) + arz[1]);
            float n_ = tanh_f((cg2 + Rn) + r_ * an);
            h = (1.f - z_) * n_ + z_ * h;
            cg0 = ng0; cg1 = ng1; cg2 = ng2;
        }
    }

    // ---- head: out[b][j] = head_b[j] + sum_k h[k]*head_w[j][k] ----
    float o = head_b[j];
#pragma unroll
    for (int k4 = 0; k4 < 16; ++k4) {
        float h0 = rl(h, 4*k4+0), h1 = rl(h, 4*k4+1);
        float h2 = rl(h, 4*k4+2), h3 = rl(h, 4*k4+3);
        const float* hw = head_w + j*64 + 4*k4;
        o += h0*hw[0] + h1*hw[1] + h2*hw[2] + h3*hw[3];
    }
    out[(size_t)b*64 + j] = o;
}

extern "C" void kernel_launch(void* const* d_in, const int* in_sizes, int n_in,
                              void* d_out, int out_size, void* d_ws, size_t ws_size,
                              hipStream_t stream) {
    const int*   seq      = (const int*)  d_in[0];
    const float* memory   = (const float*)d_in[1];
    const float* embed_w  = (const float*)d_in[2];
    const float* w_ih     = (const float*)d_in[3];
    const float* w_hh     = (const float*)d_in[4];
    const float* b_ih     = (const float*)d_in[5];
    const float* b_hh     = (const float*)d_in[6];
    const float* key_w    = (const float*)d_in[7];
    const float* key_b    = (const float*)d_in[8];
    const float* val_w    = (const float*)d_in[9];
    const float* val_b    = (const float*)d_in[10];
    const float* query_w  = (const float*)d_in[11];
    const float* query_b  = (const float*)d_in[12];
    const float* head_w   = (const float*)d_in[13];
    const float* head_b   = (const float*)d_in[14];

    char* ws = (char*)d_ws;
    __half* kT_h  = (__half*)(ws + WS_KT);
    __half* v_h   = (__half*)(ws + WS_V);
    float*  G     = (float*) (ws + WS_G);
    float4* WPhh  = (float4*)(ws + WS_WPHH);
    float4* WR    = (float4*)(ws + WS_WR);
    __half2* QPh  = (__half2*)(ws + WS_QP);
    float4* KWP   = (float4*)(ws + WS_KWP);
    float4* VWP   = (float4*)(ws + WS_VWP);

    (void)hipFuncSetAttribute((const void*)recurrent_main,
                              hipFuncAttributeMaxDynamicSharedMemorySize,
                              (int)SMEM_BYTES);

    pack_weights<<<36, 256, 0, stream>>>(w_ih, w_hh, query_w, key_w, val_w,
                                         WPhh, WR, QPh, KWP, VWP);
    build_G<<<64, 64, 0, stream>>>(embed_w, w_ih, b_ih, G);
    compute_kv<<<(B_*M_)/4, 256, 0, stream>>>(memory, key_b, val_b, KWP, VWP, kT_h, v_h);
    recurrent_main<<<B_, 64, SMEM_BYTES, stream>>>(seq, b_hh, query_b, head_w, head_b,
                                                   kT_h, v_h, G, WPhh, WR, (float*)d_out);
}

// Round 10
// 1871.096 us; speedup vs baseline: 3.6369x; 1.3184x over previous
//
#include <hip/hip_runtime.h>
#include <hip/hip_fp16.h>

// FixedFreqModel: B=512, L=2048, M=256, H=64, VOCAB=64, READ_FREQ=16.
// R10: R9 base (1 wave/batch, readlane-broadcast GRU: no LDS/barriers in the
// recurrence, fp16 kT/v/QP in 74.75KB LDS, W_hh in 192 VGPRs) with the chunk
// body SHRUNK to fit L1I (~16KB vs R9's ~42KB):
//  - GRU: `unroll 1` over 4 groups x 4 unrolled steps. Each group's 4 tokens
//    come from ONE uniform int4 load (s_load) -> no toks[16] array, no
//    cross-group pipeline regs (R8's VGPR blowup avoided). 12 named G regs
//    per group; their ~400cyc load chain hides under the group's 1st matvec.
//  - attention score/value loops unroll 4 (was 8).
//  - WR weights fp16 (halves the 48 L2 loads/chunk in the R-matvec).
// Tests the I-fetch theory cleanly: R8's test was confounded by LDS-GRU +
// scratch spills.

#define B_ 512
#define L_ 2048
#define M_ 256
#define H_ 64
#define C_ 128
#define F_ 16

typedef float v2f __attribute__((ext_vector_type(2)));

// workspace offsets (bytes)
#define WS_KT    0u            // 512*16384 halves = 16 MB
#define WS_V     16777216u     // 16 MB
#define WS_G     33554432u     // 64*192 fp32 = 48 KB
#define WS_WPHH  33603584u     // 3072 float4 = 48 KB
#define WS_WR    33652736u     // 3072 half4 (uint2) = 24 KB
#define WS_QP    33701888u     // 1024 * 8B (half4) = 8 KB
#define WS_KWP   33710080u     // 1024 float4 = 16 KB
#define WS_VWP   33726464u     // 16 KB

// dynamic LDS layout (bytes)
#define S_KT   0u        // 32768 : kT half [hh][m]   (64 x 256)
#define S_V    32768u    // 32768 : v  half [m][h]    (256 x 64)
#define S_QP   65536u    // 8192  : QP half4 [k4][j]  (16 x 64)
#define S_P    73728u    // 1024  : float4 p_s[64]
#define SMEM_BYTES 74752u

__device__ __forceinline__ float dot4(float4 a, float4 b) {
    return a.x*b.x + a.y*b.y + a.z*b.z + a.w*b.w;
}
__device__ __forceinline__ void cvt2v(uint2 raw, v2f& lo, v2f& hi) {
    __half2* hp = (__half2*)&raw;
    float2 a = __half22float2(hp[0]);
    float2 b = __half22float2(hp[1]);
    lo[0] = a.x; lo[1] = a.y; hi[0] = b.x; hi[1] = b.y;
}
__device__ __forceinline__ float fast_rcp(float x) { return __builtin_amdgcn_rcpf(x); }
__device__ __forceinline__ float sigm(float x) { return fast_rcp(1.f + __expf(-x)); }
__device__ __forceinline__ float tanh_f(float x) {
    float e2 = __expf(-2.f * fabsf(x));
    return copysignf((1.f - e2) * fast_rcp(1.f + e2), x);
}
// lane broadcast without LDS: VALU->SGPR, no memory latency
__device__ __forceinline__ float rl(float v, int lane) {
    return __int_as_float(__builtin_amdgcn_readlane(__float_as_int(v), lane));
}

// ---------------- pack weights -----------------------------------------------
__global__ void pack_weights(const float* __restrict__ w_ih,
                             const float* __restrict__ w_hh,
                             const float* __restrict__ qw,
                             const float* __restrict__ kw,
                             const float* __restrict__ vw,
                             float4* __restrict__ WPhh,
                             __half2* __restrict__ WRh,
                             __half2* __restrict__ QPh,
                             float4* __restrict__ KWP,
                             float4* __restrict__ VWP)
{
    int idx = blockIdx.x * 256 + threadIdx.x;
    if (idx < 3072) {                       // WPhh[(k4*3+g)*64+j] = w_hh[(g*64+j)][4k4..]
        int j = idx & 63, kg = idx >> 6, g = kg % 3, k4 = kg / 3;
        const float* s = w_hh + (g*64 + j)*64 + 4*k4;
        WPhh[idx] = make_float4(s[0], s[1], s[2], s[3]);
    } else if (idx < 6144) {                // WRh: fp16 retrieved-half of w_ih
        int i = idx - 3072;
        int j = i & 63, kg = i >> 6, g = kg % 3, k4 = kg / 3;
        const float* s = w_ih + (g*64 + j)*128 + 64 + 4*k4;
        WRh[i*2]     = __floats2half2_rn(s[0], s[1]);
        WRh[i*2 + 1] = __floats2half2_rn(s[2], s[3]);
    } else if (idx < 7168) {                // QPh: half4 of qw[j][4k4..]
        int i = idx - 6144;
        int j = i & 63, k4 = i >> 6;
        const float* s = qw + j*64 + 4*k4;
        QPh[i*2]     = __floats2half2_rn(s[0], s[1]);
        QPh[i*2 + 1] = __floats2half2_rn(s[2], s[3]);
    } else if (idx < 8192) {
        int i = idx - 7168;
        int j = i & 63, k4 = i >> 6;
        const float* s = kw + j*64 + 4*k4;
        KWP[i] = make_float4(s[0], s[1], s[2], s[3]);
    } else if (idx < 9216) {
        int i = idx - 8192;
        int j = i & 63, k4 = i >> 6;
        const float* s = vw + j*64 + 4*k4;
        VWP[i] = make_float4(s[0], s[1], s[2], s[3]);
    }
}

// ---------------- G[v][o] = sum_k embed[v][k]*w_ih[o][k] + b_ih[o] ----------
__global__ __launch_bounds__(64) void build_G(const float* __restrict__ embed_w,
                                              const float* __restrict__ w_ih,
                                              const float* __restrict__ b_ih,
                                              float* __restrict__ G)
{
    int v = blockIdx.x, j = threadIdx.x;
    __shared__ float e_s[64];
    e_s[j] = embed_w[v*64 + j];
    __syncthreads();
    float a0 = b_ih[j], a1 = b_ih[64 + j], a2 = b_ih[128 + j];
    for (int k = 0; k < 64; ++k) {
        float e = e_s[k];
        a0 += e * w_ih[j*128 + k];
        a1 += e * w_ih[(64 + j)*128 + k];
        a2 += e * w_ih[(128 + j)*128 + k];
    }
    G[v*192 + j]       = a0;
    G[v*192 + 64 + j]  = a1;
    G[v*192 + 128 + j] = a2;
}

// ---------------- k/v precompute (fp16 outputs) ------------------------------
__global__ __launch_bounds__(256) void compute_kv(const float* __restrict__ memory,
                                                  const float* __restrict__ key_b,
                                                  const float* __restrict__ val_b,
                                                  const float4* __restrict__ KWP,
                                                  const float4* __restrict__ VWP,
                                                  __half* __restrict__ kT_h,
                                                  __half* __restrict__ v_h)
{
    int wid = threadIdx.x >> 6;
    int o   = threadIdx.x & 63;
    int row = blockIdx.x * 4 + wid;          // row = b*256 + m
    int b = row >> 8, m = row & 255;
    __shared__ __align__(16) float mem_s[4][64];
    mem_s[wid][o] = memory[(size_t)row * 64 + o];
    __syncthreads();
    float ak = key_b[o], av = val_b[o];
    const float4* m4 = (const float4*)mem_s[wid];
#pragma unroll
    for (int k4 = 0; k4 < 16; ++k4) {
        float4 mm = m4[k4];
        ak += dot4(mm, KWP[k4*64 + o]);
        av += dot4(mm, VWP[k4*64 + o]);
    }
    kT_h[((size_t)b*64 + o)*256 + m] = __float2half(ak);  // scattered, one-time
    v_h[(size_t)row*64 + o]          = __float2half(av);  // coalesced
}

// one GRU step: h broadcast via readlane; weights in wrz/wn regs; no LDS
#define GRU_STEP(cg0, cg1, cg2) do {                                        \
    v2f arz = {bhr, bhz};                                                   \
    float an = bhn;                                                         \
    _Pragma("unroll")                                                       \
    for (int k4 = 0; k4 < 16; ++k4) {                                       \
        float h0 = rl(h, 4*k4+0), h1 = rl(h, 4*k4+1);                       \
        float h2 = rl(h, 4*k4+2), h3 = rl(h, 4*k4+3);                       \
        arz += wrz[4*k4+0] * h0; an = fmaf(h0, wn[4*k4+0], an);             \
        arz += wrz[4*k4+1] * h1; an = fmaf(h1, wn[4*k4+1], an);             \
        arz += wrz[4*k4+2] * h2; an = fmaf(h2, wn[4*k4+2], an);             \
        arz += wrz[4*k4+3] * h3; an = fmaf(h3, wn[4*k4+3], an);             \
    }                                                                       \
    float r_ = sigm((cg0 + Rr) + arz[0]);                                   \
    float z_ = sigm((cg1 + Rz) + arz[1]);                                   \
    float n_ = tanh_f((cg2 + Rn) + r_ * an);                                \
    h = (1.f - z_) * n_ + z_ * h;                                           \
} while (0)

// ---------------- main recurrent kernel: 1 wave per batch element ------------
__global__ __launch_bounds__(64, 1) void recurrent_main(
    const int*   __restrict__ seq,
    const float* __restrict__ b_hh,
    const float* __restrict__ query_b,
    const float* __restrict__ head_w,
    const float* __restrict__ head_b,
    const __half* __restrict__ kT_h,
    const __half* __restrict__ v_h,
    const float* __restrict__ G,
    const float4* __restrict__ WPhh,
    const uint2* __restrict__ WR2,    // fp16 half4 per entry
    float* __restrict__ out)
{
    const int b = blockIdx.x;
    const int j = threadIdx.x;

    extern __shared__ __align__(16) char smem[];
    const uint2* kT_u2 = (const uint2*)(smem + S_KT);   // [hh*64 + j]  (j = m-quad)
    const uint2* v_u2  = (const uint2*)(smem + S_V);    // [m*16 + o4]
    const uint2* qp_u2 = (const uint2*)(smem + S_QP);   // [k4*64 + j]
    float4* p_s4  = (float4*)(smem + S_P);

    // ---- stage kT, v (fp16) and QP into LDS once ----
    {
        const uint4* kTg = (const uint4*)(kT_h + (size_t)b * 16384);
        const uint4* vg  = (const uint4*)(v_h  + (size_t)b * 16384);
        uint4* kTls = (uint4*)(smem + S_KT);
        uint4* vls  = (uint4*)(smem + S_V);
#pragma unroll
        for (int i = 0; i < 32; ++i) {
            kTls[i*64 + j] = kTg[i*64 + j];
            vls[i*64 + j]  = vg[i*64 + j];
        }
        const uint4* qpg = (const uint4*)((const char*)WPhh + (WS_QP - WS_WPHH));
        uint4* qls = (uint4*)(smem + S_QP);
#pragma unroll
        for (int i = 0; i < 8; ++i) qls[i*64 + j] = qpg[i*64 + j];
    }

    // ---- W_hh permanently in registers: (r,z) as v2f pairs + n scalar ----
    v2f  wrz[64];
    float wn[64];
#pragma unroll
    for (int k4 = 0; k4 < 16; ++k4) {
        float4 a  = WPhh[(k4*3 + 0)*64 + j];
        float4 bq = WPhh[(k4*3 + 1)*64 + j];
        float4 cq = WPhh[(k4*3 + 2)*64 + j];
        wrz[4*k4+0][0] = a.x; wrz[4*k4+0][1] = bq.x; wn[4*k4+0] = cq.x;
        wrz[4*k4+1][0] = a.y; wrz[4*k4+1][1] = bq.y; wn[4*k4+1] = cq.y;
        wrz[4*k4+2][0] = a.z; wrz[4*k4+2][1] = bq.z; wn[4*k4+2] = cq.z;
        wrz[4*k4+3][0] = a.w; wrz[4*k4+3][1] = bq.w; wn[4*k4+3] = cq.w;
    }

    float h = 0.f;                       // lane j owns h[j]; never leaves regs
    const float bhr = b_hh[j], bhz = b_hh[64 + j], bhn = b_hh[128 + j];
    const float qb  = query_b[j];

    const int* seqb = seq + (size_t)b * L_;
    const int o4 = j & 15;        // h-quad owned in v-loop
    const int mg = j >> 4;        // m-group 0..3
    __builtin_amdgcn_wave_barrier();

    for (int c = 0; c < C_; ++c) {
        const int c16 = c * F_;

        // ---- q[j] = qb + sum_k h[k] * Wq[j][k]  (h via readlane, QP LDS) ----
        float q = qb;
#pragma unroll
        for (int k4 = 0; k4 < 16; ++k4) {
            v2f plo, phi; cvt2v(qp_u2[k4*64 + j], plo, phi);
            float h0 = rl(h, 4*k4+0), h1 = rl(h, 4*k4+1);
            float h2 = rl(h, 4*k4+2), h3 = rl(h, 4*k4+3);
            q += h0*plo[0] + h1*plo[1] + h2*phi[0] + h3*phi[1];
        }

        // ---- scores: lane j owns m = 4j..4j+3; q broadcast via readlane ----
        v2f s01 = {0.f,0.f}, s23 = {0.f,0.f};
#pragma unroll 4
        for (int hh = 0; hh < 64; ++hh) {
            float qh = rl(q, hh);
            v2f kl, kh; cvt2v(kT_u2[hh*64 + j], kl, kh);
            s01 += kl * qh; s23 += kh * qh;
        }
        const float scale = 0.125f;
        // softmax, no max-sub (|s| small), rcp not div
        float4 p;
        p.x = __expf(s01[0]*scale); p.y = __expf(s01[1]*scale);
        p.z = __expf(s23[0]*scale); p.w = __expf(s23[1]*scale);
        float sum = (p.x + p.y) + (p.z + p.w);
#pragma unroll
        for (int o = 32; o > 0; o >>= 1) sum += __shfl_xor(sum, o);
        float inv = fast_rcp(sum);
        p_s4[j] = p;
        __builtin_amdgcn_wave_barrier();

        // ---- retrieved: lane (mg,o4) over m = 4i+mg (fp16 v, packed) ----
        const float* ps = (const float*)p_s4;
        v2f aA0 = {0.f,0.f}, aB0 = {0.f,0.f};
        v2f aA1 = {0.f,0.f}, aB1 = {0.f,0.f};
#pragma unroll 4
        for (int i = 0; i < 64; i += 2) {
            int m0 = 4*i + mg, m1 = 4*(i + 1) + mg;
            float p0 = ps[m0], p1 = ps[m1];
            v2f v0l, v0h, v1l, v1h;
            cvt2v(v_u2[m0*16 + o4], v0l, v0h);
            cvt2v(v_u2[m1*16 + o4], v1l, v1h);
            aA0 += v0l * p0; aB0 += v0h * p0;
            aA1 += v1l * p1; aB1 += v1h * p1;
        }
        float4 acc;
        acc.x = (aA0[0] + aA1[0]) * inv;
        acc.y = (aA0[1] + aA1[1]) * inv;
        acc.z = (aB0[0] + aB1[0]) * inv;
        acc.w = (aB0[1] + aB1[1]) * inv;
#pragma unroll
        for (int o = 16; o <= 32; o <<= 1) {
            acc.x += __shfl_xor(acc.x, o);
            acc.y += __shfl_xor(acc.y, o);
            acc.z += __shfl_xor(acc.z, o);
            acc.w += __shfl_xor(acc.w, o);
        }
        // lane t (and t+16/32/48) holds ret[4t..4t+3] in acc

        // ---- R = W_r/z/n @ ret : ret via readlane, WR fp16 from global ----
        v2f Rrz = {0.f,0.f}; float Rn = 0.f;
#pragma unroll
        for (int k4 = 0; k4 < 16; ++k4) {
            v2f w0l, w0h, w1l, w1h, w2l, w2h;
            cvt2v(WR2[(k4*3 + 0)*64 + j], w0l, w0h);
            cvt2v(WR2[(k4*3 + 1)*64 + j], w1l, w1h);
            cvt2v(WR2[(k4*3 + 2)*64 + j], w2l, w2h);
            float r0 = rl(acc.x, k4), r1 = rl(acc.y, k4);
            float r2 = rl(acc.z, k4), r3 = rl(acc.w, k4);
            v2f t;
            t[0] = w0l[0]; t[1] = w1l[0]; Rrz += t * r0; Rn = fmaf(r0, w2l[0], Rn);
            t[0] = w0l[1]; t[1] = w1l[1]; Rrz += t * r1; Rn = fmaf(r1, w2l[1], Rn);
            t[0] = w0h[0]; t[1] = w1h[0]; Rrz += t * r2; Rn = fmaf(r2, w2h[0], Rn);
            t[0] = w0h[1]; t[1] = w1h[1]; Rrz += t * r3; Rn = fmaf(r3, w2h[1], Rn);
        }
        const float Rr = Rrz[0], Rz = Rrz[1];

        // ---- 16 GRU steps: 4 dynamic groups x 4 unrolled (I-cache friendly).
        //      Tokens: ONE uniform int4 load/group; 12 named G regs whose
        //      load chain hides under the group's first matvec. ----
#pragma unroll 1
        for (int g = 0; g < 4; ++g) {
            const int4 tg = *(const int4*)(seqb + c16 + 4*g);   // uniform s_load
            const float* GA = G + tg.x*192;
            const float* GB = G + tg.y*192;
            const float* GC = G + tg.z*192;
            const float* GD = G + tg.w*192;
            float gA0 = GA[j], gA1 = GA[64+j], gA2 = GA[128+j];
            float gB0 = GB[j], gB1 = GB[64+j], gB2 = GB[128+j];
            float gC0 = GC[j], gC1 = GC[64+j], gC2 = GC[128+j];
            float gD0 = GD[j], gD1 = GD[64+j], gD2 = GD[128+j];

            GRU_STEP(gA0, gA1, gA2);
            GRU_STEP(gB0, gB1, gB2);
            GRU_STEP(gC0, gC1, gC2);
            GRU_STEP(gD0, gD1, gD2);
        }
    }

    // ---- head: out[b][j] = head_b[j] + sum_k h[k]*head_w[j][k] ----
    float o = head_b[j];
#pragma unroll
    for (int k4 = 0; k4 < 16; ++k4) {
        float h0 = rl(h, 4*k4+0), h1 = rl(h, 4*k4+1);
        float h2 = rl(h, 4*k4+2), h3 = rl(h, 4*k4+3);
        const float* hw = head_w + j*64 + 4*k4;
        o += h0*hw[0] + h1*hw[1] + h2*hw[2] + h3*hw[3];
    }
    out[(size_t)b*64 + j] = o;
}

extern "C" void kernel_launch(void* const* d_in, const int* in_sizes, int n_in,
                              void* d_out, int out_size, void* d_ws, size_t ws_size,
                              hipStream_t stream) {
    const int*   seq      = (const int*)  d_in[0];
    const float* memory   = (const float*)d_in[1];
    const float* embed_w  = (const float*)d_in[2];
    const float* w_ih     = (const float*)d_in[3];
    const float* w_hh     = (const float*)d_in[4];
    const float* b_ih     = (const float*)d_in[5];
    const float* b_hh     = (const float*)d_in[6];
    const float* key_w    = (const float*)d_in[7];
    const float* key_b    = (const float*)d_in[8];
    const float* val_w    = (const float*)d_in[9];
    const float* val_b    = (const float*)d_in[10];
    const float* query_w  = (const float*)d_in[11];
    const float* query_b  = (const float*)d_in[12];
    const float* head_w   = (const float*)d_in[13];
    const float* head_b   = (const float*)d_in[14];

    char* ws = (char*)d_ws;
    __half* kT_h  = (__half*)(ws + WS_KT);
    __half* v_h   = (__half*)(ws + WS_V);
    float*  G     = (float*) (ws + WS_G);
    float4* WPhh  = (float4*)(ws + WS_WPHH);
    __half2* WRh  = (__half2*)(ws + WS_WR);
    __half2* QPh  = (__half2*)(ws + WS_QP);
    float4* KWP   = (float4*)(ws + WS_KWP);
    float4* VWP   = (float4*)(ws + WS_VWP);

    (void)hipFuncSetAttribute((const void*)recurrent_main,
                              hipFuncAttributeMaxDynamicSharedMemorySize,
                              (int)SMEM_BYTES);

    pack_weights<<<36, 256, 0, stream>>>(w_ih, w_hh, query_w, key_w, val_w,
                                         WPhh, WRh, QPh, KWP, VWP);
    build_G<<<64, 64, 0, stream>>>(embed_w, w_ih, b_ih, G);
    compute_kv<<<(B_*M_)/4, 256, 0, stream>>>(memory, key_b, val_b, KWP, VWP, kT_h, v_h);
    recurrent_main<<<B_, 64, SMEM_BYTES, stream>>>(seq, b_hh, query_b, head_w, head_b,
                                                   kT_h, v_h, G, WPhh,
                                                   (const uint2*)WRh, (float*)d_out);
}

// Round 12
// 1582.291 us; speedup vs baseline: 4.3007x; 1.1825x over previous
//
#include <hip/hip_runtime.h>
#include <hip/hip_fp16.h>

// FixedFreqModel: B=512, L=2048, M=256, H=64, VOCAB=64, READ_FREQ=16.
// R12 = R11 with the cvt_pkrtz return-type compile fix (auto + bit_cast).
// R11 design: R10 base (1 wave/batch, readlane-GRU, fp16 kT/v in LDS, 4x4 GRU
// groups) with all matvecs moved to v_dot2_f32_f16 (2 fp16 MACs, fp32
// accumulate, 1 inst):
//  - GRU: W_hh as half2 (96 VGPRs, was 192); h packed to half2 pairs once
//    per step (shfl+cvt_pkrtz); per k-pair: 1 readlane + 3 dot2.
//  - scores: kT stored hh-pair-interleaved (u32 = (k[2t][m],k[2t+1][m]));
//    per hh-pair: 1 ds_read_b128 + 1 readlane + 4 dot2.
//  - q/R matvecs: QP/WR half2 tables + packed h/ret pairs.
//  - v-loop, softmax, head unchanged from R10.

#define B_ 512
#define L_ 2048
#define M_ 256
#define H_ 64
#define C_ 128
#define F_ 16

typedef float v2f __attribute__((ext_vector_type(2)));
typedef _Float16 h2v __attribute__((ext_vector_type(2)));

#if __has_builtin(__builtin_amdgcn_fdot2)
__device__ __forceinline__ float FDOT2(h2v a, h2v b, float c) {
    return __builtin_amdgcn_fdot2(a, b, c, false);
}
#else
__device__ __forceinline__ float FDOT2(h2v a, h2v b, float c) {
    return c + (float)a[0]*(float)b[0] + (float)a[1]*(float)b[1];
}
#endif

__device__ __forceinline__ h2v bch(unsigned u) { return __builtin_bit_cast(h2v, u); }
__device__ __forceinline__ unsigned rl_u(unsigned v, int lane) {
    return (unsigned)__builtin_amdgcn_readlane((int)v, lane);
}
__device__ __forceinline__ float rl(float v, int lane) {
    return __int_as_float(__builtin_amdgcn_readlane(__float_as_int(v), lane));
}
// pack (mine, neighbor) -> half2 in lane order (even idx first)
__device__ __forceinline__ unsigned packpair(float mine, float other, bool odd) {
    float lo = odd ? other : mine;
    float hi = odd ? mine : other;
    auto r = __builtin_amdgcn_cvt_pkrtz(lo, hi);   // __fp16 ext_vector(2)
    return __builtin_bit_cast(unsigned, r);
}
__device__ __forceinline__ float dot4(float4 a, float4 b) {
    return a.x*b.x + a.y*b.y + a.z*b.z + a.w*b.w;
}
__device__ __forceinline__ void cvt2v(uint2 raw, v2f& lo, v2f& hi) {
    __half2* hp = (__half2*)&raw;
    float2 a = __half22float2(hp[0]);
    float2 b = __half22float2(hp[1]);
    lo[0] = a.x; lo[1] = a.y; hi[0] = b.x; hi[1] = b.y;
}
__device__ __forceinline__ float fast_rcp(float x) { return __builtin_amdgcn_rcpf(x); }
__device__ __forceinline__ float sigm(float x) { return fast_rcp(1.f + __expf(-x)); }
__device__ __forceinline__ float tanh_f(float x) {
    float e2 = __expf(-2.f * fabsf(x));
    return copysignf((1.f - e2) * fast_rcp(1.f + e2), x);
}
__device__ __forceinline__ unsigned h2rn(float a, float b) {
    __half2 h = __floats2half2_rn(a, b);
    return __builtin_bit_cast(unsigned, h);
}

// workspace offsets (bytes)
#define WS_KT    0u            // kT2: 512 * 8192 u32 = 16 MB  [b][hh2][m]
#define WS_V     16777216u     // v fp16: 16 MB [b][m][o]
#define WS_G     33554432u     // 64*192 fp32 = 48 KB
#define WS_WPHH  33603584u     // 6144 u32 = 24 KB  [(k2*3+g)*64+j]
#define WS_WR    33628160u     // 6144 u32 = 24 KB
#define WS_QP    33652736u     // 2048 u32 = 8 KB   [k2*64+j]
#define WS_KWP   33660928u     // 1024 float4 = 16 KB
#define WS_VWP   33677312u     // 16 KB

// dynamic LDS layout (bytes)
#define S_KT   0u        // 32768 : kT2 u32 [hh2=32][m=256]  (uint4 per (hh2, 4m))
#define S_V    32768u    // 32768 : v half [m][o]
#define S_QP   65536u    // 8192  : QP2 u32 [k2=32][j=64]
#define S_P    73728u    // 1024  : float4 p_s[64]
#define SMEM_BYTES 74752u

// ---------------- pack weights -----------------------------------------------
__global__ void pack_weights(const float* __restrict__ w_ih,
                             const float* __restrict__ w_hh,
                             const float* __restrict__ qw,
                             const float* __restrict__ kw,
                             const float* __restrict__ vw,
                             unsigned* __restrict__ WPhh2,
                             unsigned* __restrict__ WR2p,
                             unsigned* __restrict__ QP2,
                             float4* __restrict__ KWP,
                             float4* __restrict__ VWP)
{
    int idx = blockIdx.x * 256 + threadIdx.x;
    if (idx < 6144) {                        // WPhh2[(k2*3+g)*64+j]
        int j = idx & 63, t = idx >> 6, g = t % 3, k2 = t / 3;
        const float* s = w_hh + (g*64 + j)*64 + 2*k2;
        WPhh2[idx] = h2rn(s[0], s[1]);
    } else if (idx < 12288) {                // WR2p: retrieved half of w_ih
        int i = idx - 6144;
        int j = i & 63, t = i >> 6, g = t % 3, k2 = t / 3;
        const float* s = w_ih + (g*64 + j)*128 + 64 + 2*k2;
        WR2p[i] = h2rn(s[0], s[1]);
    } else if (idx < 14336) {                // QP2[k2*64+j]
        int i = idx - 12288;
        int j = i & 63, k2 = i >> 6;
        const float* s = qw + j*64 + 2*k2;
        QP2[i] = h2rn(s[0], s[1]);
    } else if (idx < 15360) {
        int i = idx - 14336;
        int j = i & 63, k4 = i >> 6;
        const float* s = kw + j*64 + 4*k4;
        KWP[i] = make_float4(s[0], s[1], s[2], s[3]);
    } else if (idx < 16384) {
        int i = idx - 15360;
        int j = i & 63, k4 = i >> 6;
        const float* s = vw + j*64 + 4*k4;
        VWP[i] = make_float4(s[0], s[1], s[2], s[3]);
    }
}

// ---------------- G[v][o] = sum_k embed[v][k]*w_ih[o][k] + b_ih[o] ----------
__global__ __launch_bounds__(64) void build_G(const float* __restrict__ embed_w,
                                              const float* __restrict__ w_ih,
                                              const float* __restrict__ b_ih,
                                              float* __restrict__ G)
{
    int v = blockIdx.x, j = threadIdx.x;
    __shared__ float e_s[64];
    e_s[j] = embed_w[v*64 + j];
    __syncthreads();
    float a0 = b_ih[j], a1 = b_ih[64 + j], a2 = b_ih[128 + j];
    for (int k = 0; k < 64; ++k) {
        float e = e_s[k];
        a0 += e * w_ih[j*128 + k];
        a1 += e * w_ih[(64 + j)*128 + k];
        a2 += e * w_ih[(128 + j)*128 + k];
    }
    G[v*192 + j]       = a0;
    G[v*192 + 64 + j]  = a1;
    G[v*192 + 128 + j] = a2;
}

// ---------------- k/v precompute (kT hh-pair-interleaved u32; v fp16) --------
__global__ __launch_bounds__(256) void compute_kv(const float* __restrict__ memory,
                                                  const float* __restrict__ key_b,
                                                  const float* __restrict__ val_b,
                                                  const float4* __restrict__ KWP,
                                                  const float4* __restrict__ VWP,
                                                  unsigned* __restrict__ kT2,
                                                  __half* __restrict__ v_h)
{
    int wid = threadIdx.x >> 6;
    int o   = threadIdx.x & 63;
    int row = blockIdx.x * 4 + wid;          // row = b*256 + m
    int b = row >> 8, m = row & 255;
    __shared__ __align__(16) float mem_s[4][64];
    mem_s[wid][o] = memory[(size_t)row * 64 + o];
    __syncthreads();
    float ak = key_b[o], av = val_b[o];
    const float4* m4 = (const float4*)mem_s[wid];
#pragma unroll
    for (int k4 = 0; k4 < 16; ++k4) {
        float4 mm = m4[k4];
        ak += dot4(mm, KWP[k4*64 + o]);
        av += dot4(mm, VWP[k4*64 + o]);
    }
    float nb = __shfl_xor(ak, 1);            // k[o^1][m]
    if ((o & 1) == 0)                        // pair (k[o][m], k[o+1][m])
        kT2[((size_t)b*32 + (o >> 1))*256 + m] = h2rn(ak, nb);
    v_h[(size_t)row*64 + o] = __float2half(av);
}

// one GRU step: h broadcast as half2 via readlane; dot2 matvec; no LDS
#define GRU_STEP(cg0, cg1, cg2) do {                                        \
    float gr = (cg0) + RrB, gz = (cg1) + RzB, gn = bhn;                     \
    _Pragma("unroll")                                                       \
    for (int kp = 0; kp < 32; ++kp) {                                       \
        h2v hhp = bch(rl_u(hpu, 2*kp));                                     \
        gr = FDOT2(hhp, wr2[kp], gr);                                       \
        gz = FDOT2(hhp, wz2[kp], gz);                                       \
        gn = FDOT2(hhp, wn2[kp], gn);                                       \
    }                                                                       \
    float r_ = sigm(gr);                                                    \
    float z_ = sigm(gz);                                                    \
    float n_ = tanh_f(((cg2) + Rn) + r_ * gn);                              \
    h = fmaf(z_, h - n_, n_);                                               \
    float hx_ = __shfl_xor(h, 1);                                           \
    hpu = packpair(h, hx_, odd);                                            \
} while (0)

// ---------------- main recurrent kernel: 1 wave per batch element ------------
__global__ __launch_bounds__(64, 1) void recurrent_main(
    const int*   __restrict__ seq,
    const float* __restrict__ b_hh,
    const float* __restrict__ query_b,
    const float* __restrict__ head_w,
    const float* __restrict__ head_b,
    const unsigned* __restrict__ kT2g,
    const __half* __restrict__ v_h,
    const float* __restrict__ G,
    const unsigned* __restrict__ WPhh2,
    const unsigned* __restrict__ WR2p,
    const unsigned* __restrict__ QP2g,
    float* __restrict__ out)
{
    const int b = blockIdx.x;
    const int j = threadIdx.x;
    const bool odd = (j & 1);

    extern __shared__ __align__(16) char smem[];
    const uint4* kT2_lds = (const uint4*)(smem + S_KT);  // [hh2*64 + j]: 4 m-pairs
    const uint2* v_u2    = (const uint2*)(smem + S_V);   // [m*16 + o4]
    const unsigned* qp2  = (const unsigned*)(smem + S_QP); // [k2*64 + j]
    float4* p_s4  = (float4*)(smem + S_P);

    // ---- stage kT2, v, QP2 into LDS once ----
    {
        const uint4* kTg = (const uint4*)(kT2g + (size_t)b * 8192);
        const uint4* vg  = (const uint4*)(v_h  + (size_t)b * 16384);
        uint4* kTls = (uint4*)(smem + S_KT);
        uint4* vls  = (uint4*)(smem + S_V);
#pragma unroll
        for (int i = 0; i < 32; ++i) {
            kTls[i*64 + j] = kTg[i*64 + j];
            vls[i*64 + j]  = vg[i*64 + j];
        }
        const uint4* qpg = (const uint4*)QP2g;
        uint4* qls = (uint4*)(smem + S_QP);
#pragma unroll
        for (int i = 0; i < 8; ++i) qls[i*64 + j] = qpg[i*64 + j];
    }

    // ---- W_hh in registers as half2: 96 VGPRs ----
    h2v wr2[32], wz2[32], wn2[32];
#pragma unroll
    for (int k2 = 0; k2 < 32; ++k2) {
        wr2[k2] = bch(WPhh2[(k2*3 + 0)*64 + j]);
        wz2[k2] = bch(WPhh2[(k2*3 + 1)*64 + j]);
        wn2[k2] = bch(WPhh2[(k2*3 + 2)*64 + j]);
    }

    float h = 0.f;                       // lane j owns h[j]; never leaves regs
    unsigned hpu = 0u;                   // packed (h[2t], h[2t+1]) fp16 pair
    const float bhr = b_hh[j], bhz = b_hh[64 + j], bhn = b_hh[128 + j];
    const float qb  = query_b[j];

    const int* seqb = seq + (size_t)b * L_;
    const int o4 = j & 15;        // h-quad owned in v-loop
    const int mg = j >> 4;        // m-group 0..3
    __builtin_amdgcn_wave_barrier();

    for (int c = 0; c < C_; ++c) {
        const int c16 = c * F_;

        // ---- q[j] = qb + sum_k h[k]*Wq[j][k]  (dot2: h pairs + QP2 LDS) ----
        float q = qb;
#pragma unroll 8
        for (int k2 = 0; k2 < 32; ++k2) {
            h2v pp = bch(qp2[k2*64 + j]);
            h2v hh = bch(rl_u(hpu, 2*k2));
            q = FDOT2(hh, pp, q);
        }

        // ---- scores: lane j owns m = 4j..4j+3 (dot2 over hh-pairs) ----
        float qx = __shfl_xor(q, 1);
        unsigned qpu = packpair(q, qx, odd);
        float s0 = 0.f, s1 = 0.f, s2 = 0.f, s3 = 0.f;
#pragma unroll 8
        for (int t = 0; t < 32; ++t) {
            h2v qq = bch(rl_u(qpu, 2*t));
            uint4 kk = kT2_lds[t*64 + j];
            s0 = FDOT2(bch(kk.x), qq, s0);
            s1 = FDOT2(bch(kk.y), qq, s1);
            s2 = FDOT2(bch(kk.z), qq, s2);
            s3 = FDOT2(bch(kk.w), qq, s3);
        }
        const float scale = 0.125f;
        // softmax, no max-sub (|s| small), rcp not div
        float4 p;
        p.x = __expf(s0*scale); p.y = __expf(s1*scale);
        p.z = __expf(s2*scale); p.w = __expf(s3*scale);
        float sum = (p.x + p.y) + (p.z + p.w);
#pragma unroll
        for (int o = 32; o > 0; o >>= 1) sum += __shfl_xor(sum, o);
        float inv = fast_rcp(sum);
        p_s4[j] = p;
        __builtin_amdgcn_wave_barrier();

        // ---- retrieved: lane (mg,o4) over m = 4i+mg (fp16 v, pk fp32) ----
        const float* ps = (const float*)p_s4;
        v2f aA0 = {0.f,0.f}, aB0 = {0.f,0.f};
        v2f aA1 = {0.f,0.f}, aB1 = {0.f,0.f};
#pragma unroll 4
        for (int i = 0; i < 64; i += 2) {
            int m0 = 4*i + mg, m1 = 4*(i + 1) + mg;
            float p0 = ps[m0], p1 = ps[m1];
            v2f v0l, v0h, v1l, v1h;
            cvt2v(v_u2[m0*16 + o4], v0l, v0h);
            cvt2v(v_u2[m1*16 + o4], v1l, v1h);
            aA0 += v0l * p0; aB0 += v0h * p0;
            aA1 += v1l * p1; aB1 += v1h * p1;
        }
        float4 acc;
        acc.x = (aA0[0] + aA1[0]) * inv;
        acc.y = (aA0[1] + aA1[1]) * inv;
        acc.z = (aB0[0] + aB1[0]) * inv;
        acc.w = (aB0[1] + aB1[1]) * inv;
#pragma unroll
        for (int o = 16; o <= 32; o <<= 1) {
            acc.x += __shfl_xor(acc.x, o);
            acc.y += __shfl_xor(acc.y, o);
            acc.z += __shfl_xor(acc.z, o);
            acc.w += __shfl_xor(acc.w, o);
        }
        // lane t (and t+16/32/48) holds ret[4t..4t+3] in acc

        // ---- R matvec: ret packed fp16 pairs + WR2p global (dot2) ----
        unsigned rp0 = packpair(acc.x, acc.y, false);  // (ret[4t], ret[4t+1])
        unsigned rp1 = packpair(acc.z, acc.w, false);  // (ret[4t+2], ret[4t+3])
        float Rr = 0.f, Rz = 0.f, Rn = 0.f;
#pragma unroll 8
        for (int k2 = 0; k2 < 32; ++k2) {
            unsigned rsel = (k2 & 1) ? rp1 : rp0;
            h2v rr = bch(rl_u(rsel, k2 >> 1));
            Rr = FDOT2(rr, bch(WR2p[(k2*3 + 0)*64 + j]), Rr);
            Rz = FDOT2(rr, bch(WR2p[(k2*3 + 1)*64 + j]), Rz);
            Rn = FDOT2(rr, bch(WR2p[(k2*3 + 2)*64 + j]), Rn);
        }
        const float RrB = Rr + bhr, RzB = Rz + bhz;

        // ---- 16 GRU steps: 4 dynamic groups x 4 unrolled (I-cache OK).
        //      Tokens: one uniform int4 load/group; 12 named G regs. ----
#pragma unroll 1
        for (int g = 0; g < 4; ++g) {
            const int4 tg = *(const int4*)(seqb + c16 + 4*g);
            const float* GA = G + tg.x*192;
            const float* GB = G + tg.y*192;
            const float* GC = G + tg.z*192;
            const float* GD = G + tg.w*192;
            float gA0 = GA[j], gA1 = GA[64+j], gA2 = GA[128+j];
            float gB0 = GB[j], gB1 = GB[64+j], gB2 = GB[128+j];
            float gC0 = GC[j], gC1 = GC[64+j], gC2 = GC[128+j];
            float gD0 = GD[j], gD1 = GD[64+j], gD2 = GD[128+j];

            GRU_STEP(gA0, gA1, gA2);
            GRU_STEP(gB0, gB1, gB2);
            GRU_STEP(gC0, gC1, gC2);
            GRU_STEP(gD0, gD1, gD2);
        }
    }

    // ---- head: out[b][j] = head_b[j] + sum_k h[k]*head_w[j][k] (fp32) ----
    float o = head_b[j];
#pragma unroll
    for (int k4 = 0; k4 < 16; ++k4) {
        float h0 = rl(h, 4*k4+0), h1 = rl(h, 4*k4+1);
        float h2 = rl(h, 4*k4+2), h3 = rl(h, 4*k4+3);
        const float* hw = head_w + j*64 + 4*k4;
        o += h0*hw[0] + h1*hw[1] + h2*hw[2] + h3*hw[3];
    }
    out[(size_t)b*64 + j] = o;
}

extern "C" void kernel_launch(void* const* d_in, const int* in_sizes, int n_in,
                              void* d_out, int out_size, void* d_ws, size_t ws_size,
                              hipStream_t stream) {
    const int*   seq      = (const int*)  d_in[0];
    const float* memory   = (const float*)d_in[1];
    const float* embed_w  = (const float*)d_in[2];
    const float* w_ih     = (const float*)d_in[3];
    const float* w_hh     = (const float*)d_in[4];
    const float* b_ih     = (const float*)d_in[5];
    const float* b_hh     = (const float*)d_in[6];
    const float* key_w    = (const float*)d_in[7];
    const float* key_b    = (const float*)d_in[8];
    const float* val_w    = (const float*)d_in[9];
    const float* val_b    = (const float*)d_in[10];
    const float* query_w  = (const float*)d_in[11];
    const float* query_b  = (const float*)d_in[12];
    const float* head_w   = (const float*)d_in[13];
    const float* head_b   = (const float*)d_in[14];

    char* ws = (char*)d_ws;
    unsigned* kT2  = (unsigned*)(ws + WS_KT);
    __half*   v_h  = (__half*)  (ws + WS_V);
    float*    G    = (float*)   (ws + WS_G);
    unsigned* WPhh2 = (unsigned*)(ws + WS_WPHH);
    unsigned* WR2p  = (unsigned*)(ws + WS_WR);
    unsigned* QP2   = (unsigned*)(ws + WS_QP);
    float4*   KWP   = (float4*)  (ws + WS_KWP);
    float4*   VWP   = (float4*)  (ws + WS_VWP);

    (void)hipFuncSetAttribute((const void*)recurrent_main,
                              hipFuncAttributeMaxDynamicSharedMemorySize,
                              (int)SMEM_BYTES);

    pack_weights<<<64, 256, 0, stream>>>(w_ih, w_hh, query_w, key_w, val_w,
                                         WPhh2, WR2p, QP2, KWP, VWP);
    build_G<<<64, 64, 0, stream>>>(embed_w, w_ih, b_ih, G);
    compute_kv<<<(B_*M_)/4, 256, 0, stream>>>(memory, key_b, val_b, KWP, VWP, kT2, v_h);
    recurrent_main<<<B_, 64, SMEM_BYTES, stream>>>(seq, b_hh, query_b, head_w, head_b,
                                                   kT2, v_h, G, WPhh2, WR2p, QP2,
                                                   (float*)d_out);
}